// Round 11
// baseline (354.624 us; speedup 1.0000x reference)
//
#include <hip/hip_runtime.h>
#include <stdint.h>

typedef float v4f __attribute__((ext_vector_type(4)));
typedef __bf16 v8bf __attribute__((ext_vector_type(8)));
typedef __bf16 v4bf __attribute__((ext_vector_type(4)));
typedef unsigned short v8us __attribute__((ext_vector_type(8)));
typedef unsigned short v4us __attribute__((ext_vector_type(4)));

__device__ __forceinline__ float b2f(unsigned short u) {
    union { float f; uint32_t i; } x; x.i = ((uint32_t)u) << 16; return x.f;
}
__device__ __forceinline__ unsigned short f2b(float f) {
    union { float f; uint32_t u; } x; x.f = f;
    uint32_t r = x.u + 0x7fffu + ((x.u >> 16) & 1u);
    return (unsigned short)(r >> 16);
}

// async global->LDS, 16B/lane. LDS dst must be wave-uniform; HW adds lane*16.
__device__ __forceinline__ void gload16(const unsigned short* g, unsigned short* l) {
    __builtin_amdgcn_global_load_lds(
        (const __attribute__((address_space(1))) void*)g,
        (__attribute__((address_space(3))) void*)l,
        16, 0, 0);
}

// ---------------------------------------------------------------------------
// Transpose tile body: W[K][N] fp32 -> WT[N][K] bf16, one 64x64 tile.
// ---------------------------------------------------------------------------
__device__ __forceinline__ void transpose_tile(
    const float* __restrict__ W, unsigned short* __restrict__ WT,
    int K, int N, int kb, int nb, int tid)
{
    __shared__ unsigned short t[64][65];
    const int r = tid >> 4, c4 = (tid & 15) * 4;
    #pragma unroll
    for (int i = 0; i < 4; ++i) {
        int k = r + i * 16;
        float4 v = *(const float4*)&W[(size_t)(kb + k) * N + nb + c4];
        t[c4 + 0][k] = f2b(v.x);
        t[c4 + 1][k] = f2b(v.y);
        t[c4 + 2][k] = f2b(v.z);
        t[c4 + 3][k] = f2b(v.w);
    }
    __syncthreads();
    #pragma unroll
    for (int i = 0; i < 4; ++i) {
        int n = r + i * 16;
        v4us o = {t[n][c4], t[n][c4 + 1], t[n][c4 + 2], t[n][c4 + 3]};
        *(v4us*)&WT[(size_t)(nb + n) * K + kb + c4] = o;
    }
}

// ---------------------------------------------------------------------------
// r21 prep_fused: x convert (4096 blocks) + WqkvT (768) + W1T (1024) +
// WoT (256) in ONE launch. Block-uniform branch.
// ---------------------------------------------------------------------------
__global__ __launch_bounds__(256) void prep_fused(
    const float* __restrict__ x, unsigned short* __restrict__ xb,
    const float* __restrict__ Wqkv, unsigned short* __restrict__ WqkvT,
    const float* __restrict__ W1, unsigned short* __restrict__ W1T,
    const float* __restrict__ Wo, unsigned short* __restrict__ WoT)
{
    const int b = blockIdx.x, tid = threadIdx.x;
    if (b < 4096) {
        int i = (b * 256 + tid) * 4;
        float4 v = *(const float4*)&x[i];
        v4us o = {f2b(v.x), f2b(v.y), f2b(v.z), f2b(v.w)};
        *(v4us*)&xb[i] = o;
    } else if (b < 4096 + 768) {
        int lb = b - 4096;                       // Wqkv: 48 x 16 tiles
        transpose_tile(Wqkv, WqkvT, 1024, 3072, (lb / 48) * 64, (lb % 48) * 64, tid);
    } else if (b < 4096 + 768 + 1024) {
        int lb = b - 4096 - 768;                 // W1: 64 x 16 tiles
        transpose_tile(W1, W1T, 1024, 4096, (lb / 64) * 64, (lb % 64) * 64, tid);
    } else {
        int lb = b - 4096 - 768 - 1024;          // Wo: 16 x 16 tiles
        transpose_tile(Wo, WoT, 1024, 1024, (lb / 16) * 64, (lb % 16) * 64, tid);
    }
}

// ---------------------------------------------------------------------------
// XCD-locality swizzle for GEMM grids (validated r14). MB must be %8.
// ---------------------------------------------------------------------------
__device__ __forceinline__ void xcd_swizzle(int& bm, int& bn) {
    int NB = gridDim.x, MB = gridDim.y;
    int flat = blockIdx.x + NB * blockIdx.y;
    int xcd = flat & 7, j = flat >> 3;
    int MBand = MB >> 3;
    bm = xcd * MBand + (j % MBand);
    bn = j / MBand;
}

// ---------------------------------------------------------------------------
// 128x64-tile GEMM for narrow-N (N=1024), BK=64. r20: depth-2 prefetch +
// single-barrier dbuf with STATIC register indexing (rule #20). K %128.
// ---------------------------------------------------------------------------
__global__ __launch_bounds__(256) void gemm_bt_n64(
    const unsigned short* __restrict__ A, const unsigned short* __restrict__ BT,
    const float* __restrict__ bias, unsigned short* __restrict__ C,
    int M, int N, int K, int relu)
{
    __shared__ __align__(16) unsigned short sA0[2][128 * 32];
    __shared__ __align__(16) unsigned short sB0[2][64 * 32];
    __shared__ __align__(16) unsigned short sA1[2][128 * 32];
    __shared__ __align__(16) unsigned short sB1[2][64 * 32];
    const int tid  = threadIdx.x;
    const int wave = tid >> 6, lane = tid & 63;
    const int wm = wave >> 1, wn = wave & 1;
    const int quad = lane >> 4, l16 = lane & 15;
    int bm, bn;
    xcd_swizzle(bm, bn);

    const int srow = lane >> 2, scol = (lane & 3) * 8;
    const unsigned short* ga0 = A  + (size_t)(bm * 128 + (wave * 2 + 0) * 16 + srow) * K + scol;
    const unsigned short* ga1 = A  + (size_t)(bm * 128 + (wave * 2 + 1) * 16 + srow) * K + scol;
    const unsigned short* gb0 = BT + (size_t)(bn * 64 + wave * 16 + srow) * K + scol;
    const int oa0 = (wave * 2 + 0) * 512 + lane * 8;
    const int oa1 = (wave * 2 + 1) * 512 + lane * 8;
    const int ob  = wave * 512 + lane * 8;

    v8us aR0[2][2], bR0[2], aR1[2][2], bR1[2];
    #pragma unroll
    for (int c = 0; c < 2; ++c) {
        aR0[c][0] = *(const v8us*)(ga0 + c * 32);
        aR0[c][1] = *(const v8us*)(ga1 + c * 32);
        bR0[c]    = *(const v8us*)(gb0 + c * 32);
        aR1[c][0] = *(const v8us*)(ga0 + 64 + c * 32);
        aR1[c][1] = *(const v8us*)(ga1 + 64 + c * 32);
        bR1[c]    = *(const v8us*)(gb0 + 64 + c * 32);
    }

    v4f acc[4][2];
    #pragma unroll
    for (int i = 0; i < 4; ++i)
        #pragma unroll
        for (int j = 0; j < 2; ++j)
            acc[i][j] = (v4f){0.f, 0.f, 0.f, 0.f};

    for (int kt = 0; kt < K; kt += 128) {
        // ---- half 0 ----
        #pragma unroll
        for (int c = 0; c < 2; ++c) {
            *(v8us*)&sA0[c][oa0] = aR0[c][0];
            *(v8us*)&sA0[c][oa1] = aR0[c][1];
            *(v8us*)&sB0[c][ob]  = bR0[c];
        }
        __syncthreads();
        if (kt + 128 < K) {
            const int kn = kt + 128;
            #pragma unroll
            for (int c = 0; c < 2; ++c) {
                aR0[c][0] = *(const v8us*)(ga0 + kn + c * 32);
                aR0[c][1] = *(const v8us*)(ga1 + kn + c * 32);
                bR0[c]    = *(const v8us*)(gb0 + kn + c * 32);
            }
        }
        #pragma unroll
        for (int c = 0; c < 2; ++c) {
            v8bf af[4], bfr[2];
            #pragma unroll
            for (int mt = 0; mt < 4; ++mt)
                af[mt] = *(const v8bf*)&sA0[c][(wm * 64 + mt * 16 + l16) * 32 + quad * 8];
            #pragma unroll
            for (int nt = 0; nt < 2; ++nt)
                bfr[nt] = *(const v8bf*)&sB0[c][(wn * 32 + nt * 16 + l16) * 32 + quad * 8];
            #pragma unroll
            for (int mt = 0; mt < 4; ++mt)
                #pragma unroll
                for (int nt = 0; nt < 2; ++nt)
                    acc[mt][nt] = __builtin_amdgcn_mfma_f32_16x16x32_bf16(
                        af[mt], bfr[nt], acc[mt][nt], 0, 0, 0);
        }

        // ---- half 1 ----
        #pragma unroll
        for (int c = 0; c < 2; ++c) {
            *(v8us*)&sA1[c][oa0] = aR1[c][0];
            *(v8us*)&sA1[c][oa1] = aR1[c][1];
            *(v8us*)&sB1[c][ob]  = bR1[c];
        }
        __syncthreads();
        if (kt + 192 < K) {
            const int kn = kt + 192;
            #pragma unroll
            for (int c = 0; c < 2; ++c) {
                aR1[c][0] = *(const v8us*)(ga0 + kn + c * 32);
                aR1[c][1] = *(const v8us*)(ga1 + kn + c * 32);
                bR1[c]    = *(const v8us*)(gb0 + kn + c * 32);
            }
        }
        #pragma unroll
        for (int c = 0; c < 2; ++c) {
            v8bf af[4], bfr[2];
            #pragma unroll
            for (int mt = 0; mt < 4; ++mt)
                af[mt] = *(const v8bf*)&sA1[c][(wm * 64 + mt * 16 + l16) * 32 + quad * 8];
            #pragma unroll
            for (int nt = 0; nt < 2; ++nt)
                bfr[nt] = *(const v8bf*)&sB1[c][(wn * 32 + nt * 16 + l16) * 32 + quad * 8];
            #pragma unroll
            for (int mt = 0; mt < 4; ++mt)
                #pragma unroll
                for (int nt = 0; nt < 2; ++nt)
                    acc[mt][nt] = __builtin_amdgcn_mfma_f32_16x16x32_bf16(
                        af[mt], bfr[nt], acc[mt][nt], 0, 0, 0);
        }
    }

    #pragma unroll
    for (int mt = 0; mt < 4; ++mt) {
        #pragma unroll
        for (int nt = 0; nt < 2; ++nt) {
            int col = bn * 64 + wn * 32 + nt * 16 + l16;
            float bv = bias ? bias[col] : 0.f;
            #pragma unroll
            for (int r = 0; r < 4; ++r) {
                int row = bm * 128 + wm * 64 + mt * 16 + quad * 4 + r;
                float v = acc[mt][nt][r] + bv;
                if (relu) v = fmaxf(v, 0.f);
                C[(size_t)row * N + col] = f2b(v);
            }
        }
    }
}

// ---------------------------------------------------------------------------
// r24 gemm128: the literal m97 structure (measured 874-912 TF on 4096^3).
// 128x128 tile, 256 thr / 4 waves (2M x 2N), BK=64 dual-chunk, SINGLE LDS
// buffer (32KB -> ~3 blocks/CU at ~160 VGPR), global_load_lds-16 staging
// between two barriers. Cross-block overlap (m114, ~3 blocks/CU) hides the
// per-tile vmcnt drain — the mechanism our 256^2 1-block/CU gemm256 lacked
// ("128^2 for simple 2-barrier loops, 256^2 for deep-pipelined" — m103).
// Staging + st_16x32 swizzle identical to r16-verified gemm256 machinery;
// epilogue (incl SPLIT_V) identical to round-0-verified gemm_bt.
// grid: (N/128, M/128), MB %8.
// ---------------------------------------------------------------------------
template<int SPLIT_V>
__global__ __launch_bounds__(256) void gemm128(
    const unsigned short* __restrict__ A, const unsigned short* __restrict__ BT,
    const float* __restrict__ bias, unsigned short* __restrict__ C,
    unsigned short* __restrict__ VT, int M, int N, int K, int relu)
{
    __shared__ __align__(16) unsigned short sA[128 * 64];
    __shared__ __align__(16) unsigned short sB[128 * 64];
    const int tid  = threadIdx.x;
    const int wave = tid >> 6, lane = tid & 63;
    const int wm = wave >> 1, wn = wave & 1;
    const int quad = lane >> 4, l16 = lane & 15;
    int bm, bn;
    xcd_swizzle(bm, bn);

    // staging (gemm256-identical pattern): wave w covers rows w*32..w*32+31,
    // 4 issues of 8 rows x 64 cols (1KB). lane -> row j*8+(lane>>3), phys col
    // (lane&7)*8, global source col pre-swizzled ^16 iff row&4 (<=> lane>=32).
    const int srow = lane >> 3;
    const int scol = ((lane & 7) * 8) ^ ((lane & 32) ? 16 : 0);
    size_t aoff[4], boff[4];
    #pragma unroll
    for (int j = 0; j < 4; ++j) {
        int r = wave * 32 + j * 8 + srow;
        aoff[j] = (size_t)(bm * 128 + r) * K + scol;
        boff[j] = (size_t)(bn * 128 + r) * K + scol;
    }
    const int lds0 = wave * 32 * 64;   // shorts; +j*512 per issue

    // ds_read swizzle: logical k-col quad*8 -> phys ^16 iff row&4 (= l16&4)
    const int ksw = (quad * 8) ^ ((l16 & 4) ? 16 : 0);

    v4f acc[4][4];
    #pragma unroll
    for (int i = 0; i < 4; ++i)
        #pragma unroll
        for (int j = 0; j < 4; ++j)
            acc[i][j] = (v4f){0.f, 0.f, 0.f, 0.f};

    for (int kt = 0; kt < K; kt += 64) {
        __syncthreads();   // prior iter's reads of sA/sB done
        #pragma unroll
        for (int j = 0; j < 4; ++j)
            gload16(A  + aoff[j] + kt, &sA[lds0 + j * 512]);
        #pragma unroll
        for (int j = 0; j < 4; ++j)
            gload16(BT + boff[j] + kt, &sB[lds0 + j * 512]);
        __syncthreads();   // drains vmcnt(0): tile landed (hidden by other blocks)

        v8bf af[4][2], bfr[4][2];
        #pragma unroll
        for (int mt = 0; mt < 4; ++mt)
            #pragma unroll
            for (int kc = 0; kc < 2; ++kc)
                af[mt][kc] = *(const v8bf*)&sA[
                    (wm * 64 + mt * 16 + l16) * 64 + kc * 32 + ksw];
        #pragma unroll
        for (int nt = 0; nt < 4; ++nt)
            #pragma unroll
            for (int kc = 0; kc < 2; ++kc)
                bfr[nt][kc] = *(const v8bf*)&sB[
                    (wn * 64 + nt * 16 + l16) * 64 + kc * 32 + ksw];
        #pragma unroll
        for (int mt = 0; mt < 4; ++mt)
            #pragma unroll
            for (int nt = 0; nt < 4; ++nt)
                #pragma unroll
                for (int kc = 0; kc < 2; ++kc)
                    acc[mt][nt] = __builtin_amdgcn_mfma_f32_16x16x32_bf16(
                        af[mt][kc], bfr[nt][kc], acc[mt][nt], 0, 0, 0);
    }

    #pragma unroll
    for (int mt = 0; mt < 4; ++mt) {
        int row = bm * 128 + wm * 64 + mt * 16 + quad * 4;
        #pragma unroll
        for (int nt = 0; nt < 4; ++nt) {
            int c0 = bn * 128 + wn * 64 + nt * 16;
            int col = c0 + l16;
            float bv = bias ? bias[col] : 0.f;
            if (SPLIT_V && (c0 % 192) >= 128) {
                int hh = c0 / 192;
                int d  = (c0 % 192) - 128 + l16;
                int bb = row >> 11;
                int s  = row & 2047;
                v4us st;
                #pragma unroll
                for (int r = 0; r < 4; ++r)
                    st[r] = f2b(acc[mt][nt][r] + bv);
                *(v4us*)&VT[((size_t)(bb * 16 + hh) * 64 + d) * 2048 + s] = st;
            } else {
                float qs = (SPLIT_V && (c0 % 192) < 64) ? 0.18033688f : 1.0f;
                #pragma unroll
                for (int r = 0; r < 4; ++r) {
                    float v = (acc[mt][nt][r] + bv) * qs;
                    if (relu) v = fmaxf(v, 0.f);
                    C[(size_t)(row + r) * N + col] = f2b(v);
                }
            }
        }
    }
}

// ---------------------------------------------------------------------------
// MFMA flash attention v11 (r18): 512 threads / 8 waves, 16 q/wave, grid 512,
// single-barrier double-buffered K/V LDS. LDS 55296 B -> 2 blocks/CU.
// ---------------------------------------------------------------------------
__global__ __launch_bounds__(512) void attn_mfma(
    const unsigned short* __restrict__ qkv, const unsigned short* __restrict__ VT,
    unsigned short* __restrict__ av)
{
    __shared__ __align__(16) unsigned short sK[2][64 * 72];
    __shared__ __align__(16) unsigned short sVT[2][64 * 72];
    __shared__ __align__(16) unsigned short sP[8][16 * 72];
    const int tid  = threadIdx.x;
    const int wave = tid >> 6, lane = tid & 63;
    const int quad = lane >> 4, l16 = lane & 15;
    const int blk = blockIdx.x;
    const int xcd = blk & 7, local = blk >> 3;
    const int bh = xcd * 4 + (local & 3);     // all q-blocks of a bh on one XCD
    const int qb = local >> 2;                // [0,16): 128-row q-block
    const int h = bh & 15, b = bh >> 4;
    const int row0 = b * 2048;
    const int qbase = row0 + qb * 128 + wave * 16;
    const size_t qoff = (size_t)h * 192;
    const size_t koff = qoff + 64;

    v8bf qf[2];
    #pragma unroll
    for (int kc = 0; kc < 2; ++kc)
        qf[kc] = *(const v8bf*)&qkv[(size_t)(qbase + l16) * 3072
                                    + qoff + kc * 32 + quad * 8];

    v4f o[4];
    #pragma unroll
    for (int dt = 0; dt < 4; ++dt)
        o[dt] = (v4f){0.f, 0.f, 0.f, 0.f};
    float ll = 0.f;

    // staging: 512 threads cover 64x64 K tile and 64x64 V tile, 1 v8us each
    const int k_key = tid >> 3, k_oct = (tid & 7) * 8;
    const unsigned short* gK = qkv + (size_t)(row0 + k_key) * 3072 + koff + k_oct;
    const unsigned short* gV = VT + ((size_t)bh * 64 + k_key) * 2048 + k_oct;
    const size_t stepK = (size_t)64 * 3072;
    const size_t stepV = 64;

    v8us kreg = *(const v8us*)gK;
    v8us vreg = *(const v8us*)gV;
    gK += stepK; gV += stepV;

    for (int kt = 0; kt < 32; ++kt) {
        const int cur = kt & 1;
        *(v8us*)&sK[cur][k_key * 72 + k_oct]  = kreg;
        *(v8us*)&sVT[cur][k_key * 72 + k_oct] = vreg;
        __syncthreads();
        if (kt < 31) {
            kreg = *(const v8us*)gK;
            vreg = *(const v8us*)gV;
            gK += stepK; gV += stepV;
        }

        v4f sc[4];
        #pragma unroll
        for (int kk = 0; kk < 4; ++kk) {
            sc[kk] = (v4f){0.f, 0.f, 0.f, 0.f};
            #pragma unroll
            for (int kc = 0; kc < 2; ++kc) {
                v8bf ak = *(const v8bf*)&sK[cur][(kk * 16 + l16) * 72 + kc * 32 + quad * 8];
                sc[kk] = __builtin_amdgcn_mfma_f32_16x16x32_bf16(
                    ak, qf[kc], sc[kk], 0, 0, 0);
            }
        }

        float ps = 0.f;
        #pragma unroll
        for (int kk = 0; kk < 4; ++kk) {
            v4bf pk;
            #pragma unroll
            for (int rr = 0; rr < 4; ++rr) {
                float p = __builtin_amdgcn_exp2f(sc[kk][rr]);
                ps += p;
                pk[rr] = (__bf16)p;
            }
            *(v4bf*)&sP[wave][l16 * 72 + kk * 16 + quad * 4] = pk;
        }
        ll += ps;

        __asm__ volatile("s_waitcnt lgkmcnt(0)" ::: "memory");

        #pragma unroll
        for (int c = 0; c < 2; ++c) {
            union { v8bf v; v8us u; } u;
            u.u = *(const v8us*)&sP[wave][l16 * 72 + c * 32 + quad * 8];
            v8bf pb = u.v;
            #pragma unroll
            for (int dt = 0; dt < 4; ++dt) {
                v8bf va = *(const v8bf*)&sVT[cur][(dt * 16 + l16) * 72 + c * 32 + quad * 8];
                o[dt] = __builtin_amdgcn_mfma_f32_16x16x32_bf16(
                    va, pb, o[dt], 0, 0, 0);
            }
        }
    }

    float l = ll;
    l += __shfl_xor(l, 16, 64);
    l += __shfl_xor(l, 32, 64);
    float inv = 1.f / l;
    int qrow = qbase + l16;
    #pragma unroll
    for (int dt = 0; dt < 4; ++dt) {
        v4bf st;
        #pragma unroll
        for (int rr = 0; rr < 4; ++rr)
            st[rr] = (__bf16)(o[dt][rr] * inv);
        *(v4bf*)&av[(size_t)qrow * 1024 + h * 64 + dt * 16 + quad * 4] = st;
    }
}

// ---------------------------------------------------------------------------
// LN1 body (residual f32, out bf16, in-place safe).
// ---------------------------------------------------------------------------
__device__ __forceinline__ void ln_row_f32res(
    const unsigned short* __restrict__ a, const float* __restrict__ resid,
    const float* __restrict__ gamma, const float* __restrict__ beta,
    unsigned short* __restrict__ outp, int row, int tid)
{
    const size_t base = (size_t)row * 1024;
    const int c0 = tid * 4;
    ushort4 avv = *(const ushort4*)&a[base + c0];
    float4 rv = *(const float4*)&resid[base + c0];
    float y[4];
    y[0] = b2f(avv.x) + rv.x;
    y[1] = b2f(avv.y) + rv.y;
    y[2] = b2f(avv.z) + rv.z;
    y[3] = b2f(avv.w) + rv.w;
    float s  = y[0] + y[1] + y[2] + y[3];
    float ss = y[0]*y[0] + y[1]*y[1] + y[2]*y[2] + y[3]*y[3];
    #pragma unroll
    for (int off = 32; off; off >>= 1) {
        s  += __shfl_xor(s, off, 64);
        ss += __shfl_xor(ss, off, 64);
    }
    __shared__ float red[8];
    int wave = tid >> 6, lane = tid & 63;
    if (lane == 0) { red[wave] = s; red[4 + wave] = ss; }
    __syncthreads();
    s  = red[0] + red[1] + red[2] + red[3];
    ss = red[4] + red[5] + red[6] + red[7];
    float mean = s * (1.f / 1024.f);
    float var  = ss * (1.f / 1024.f) - mean * mean;
    float rstd = rsqrtf(var + 1e-5f);
    float4 gv = *(const float4*)&gamma[c0];
    float4 bv = *(const float4*)&beta[c0];
    ushort4 ov;
    ov.x = f2b(gv.x * (y[0] - mean) * rstd + bv.x);
    ov.y = f2b(gv.y * (y[1] - mean) * rstd + bv.y);
    ov.z = f2b(gv.z * (y[2] - mean) * rstd + bv.z);
    ov.w = f2b(gv.w * (y[3] - mean) * rstd + bv.w);
    *(ushort4*)&outp[base + c0] = ov;
}

// ---------------------------------------------------------------------------
// r23: LN1 (4096 rows) + W2T transpose (1024 tiles) fused into one launch.
// ---------------------------------------------------------------------------
__global__ __launch_bounds__(256) void ln1_w2t_fused(
    const unsigned short* __restrict__ a, const float* __restrict__ x,
    const float* __restrict__ gamma, const float* __restrict__ beta,
    unsigned short* __restrict__ h_out,
    const float* __restrict__ W2, unsigned short* __restrict__ W2T)
{
    const int b = blockIdx.x, tid = threadIdx.x;
    if (b < 4096) {
        ln_row_f32res(a, x, gamma, beta, h_out, b, tid);
    } else {
        int lb = b - 4096;                       // W2: [4096][1024] -> 64x16 tiles
        transpose_tile(W2, W2T, 4096, 1024, (lb / 16) * 64, (lb % 16) * 64, tid);
    }
}

// ---------------------------------------------------------------------------
// Fused residual-add + LayerNorm (standalone, used for LN2).
// ---------------------------------------------------------------------------
template<int RES_F32, int OUT_F32>
__global__ __launch_bounds__(256) void ln_fused(
    const unsigned short* __restrict__ a, const void* __restrict__ residv,
    const float* __restrict__ gamma, const float* __restrict__ beta,
    void* __restrict__ outv)
{
    const int row = blockIdx.x, tid = threadIdx.x;
    const size_t base = (size_t)row * 1024;
    const int c0 = tid * 4;
    ushort4 avv = *(const ushort4*)&a[base + c0];
    float y[4];
    if (RES_F32) {
        float4 rv = *(const float4*)((const float*)residv + base + c0);
        y[0] = b2f(avv.x) + rv.x;
        y[1] = b2f(avv.y) + rv.y;
        y[2] = b2f(avv.z) + rv.z;
        y[3] = b2f(avv.w) + rv.w;
    } else {
        ushort4 rv = *(const ushort4*)((const unsigned short*)residv + base + c0);
        y[0] = b2f(avv.x) + b2f(rv.x);
        y[1] = b2f(avv.y) + b2f(rv.y);
        y[2] = b2f(avv.z) + b2f(rv.z);
        y[3] = b2f(avv.w) + b2f(rv.w);
    }
    float s  = y[0] + y[1] + y[2] + y[3];
    float ss = y[0]*y[0] + y[1]*y[1] + y[2]*y[2] + y[3]*y[3];
    #pragma unroll
    for (int off = 32; off; off >>= 1) {
        s  += __shfl_xor(s, off, 64);
        ss += __shfl_xor(ss, off, 64);
    }
    __shared__ float red[8];
    int wave = tid >> 6, lane = tid & 63;
    if (lane == 0) { red[wave] = s; red[4 + wave] = ss; }
    __syncthreads();
    s  = red[0] + red[1] + red[2] + red[3];
    ss = red[4] + red[5] + red[6] + red[7];
    float mean = s * (1.f / 1024.f);
    float var  = ss * (1.f / 1024.f) - mean * mean;
    float rstd = rsqrtf(var + 1e-5f);
    float4 gv = *(const float4*)&gamma[c0];
    float4 bv = *(const float4*)&beta[c0];
    float r0 = gv.x * (y[0] - mean) * rstd + bv.x;
    float r1 = gv.y * (y[1] - mean) * rstd + bv.y;
    float r2 = gv.z * (y[2] - mean) * rstd + bv.z;
    float r3 = gv.w * (y[3] - mean) * rstd + bv.w;
    if (OUT_F32) {
        float4 ov = {r0, r1, r2, r3};
        *(float4*)((float*)outv + base + c0) = ov;
    } else {
        ushort4 ov;
        ov.x = f2b(r0); ov.y = f2b(r1); ov.z = f2b(r2); ov.w = f2b(r3);
        *(ushort4*)((unsigned short*)outv + base + c0) = ov;
    }
}

// ---------------------------------------------------------------------------
// r24 pipeline (8 launches), ws map as r21:
//  R0[0..12M): qkv Q/K -> ffn1(16M)
//  R0[12M..15M): WqkvT   R0[15M..16M): WoT
//  R1: VT -> attn_out -> h (LN1 in-place) -> residual for LN2
//  R2: xb -> av -> W2T
//  R3: W1T -> ffn2
// ---------------------------------------------------------------------------
extern "C" void kernel_launch(void* const* d_in, const int* in_sizes, int n_in,
                              void* d_out, int out_size, void* d_ws, size_t ws_size,
                              hipStream_t stream)
{
    (void)in_sizes; (void)n_in; (void)out_size; (void)ws_size;
    const float* x    = (const float*)d_in[0];
    const float* Wqkv = (const float*)d_in[1];
    const float* bqkv = (const float*)d_in[2];
    const float* Wo   = (const float*)d_in[3];
    const float* bo   = (const float*)d_in[4];
    const float* g1   = (const float*)d_in[5];
    const float* be1  = (const float*)d_in[6];
    const float* W1   = (const float*)d_in[7];
    const float* b1   = (const float*)d_in[8];
    const float* W2   = (const float*)d_in[9];
    const float* b2   = (const float*)d_in[10];
    const float* g2   = (const float*)d_in[11];
    const float* be2  = (const float*)d_in[12];
    float* out = (float*)d_out;

    unsigned short* R0 = (unsigned short*)d_ws;
    unsigned short* R1 = R0 + (size_t)16 * 1024 * 1024;
    unsigned short* R2 = R1 + (size_t)4 * 1024 * 1024;
    unsigned short* R3 = R2 + (size_t)4 * 1024 * 1024;
    unsigned short* WqkvT = R0 + (size_t)12 * 1024 * 1024;
    unsigned short* WoT   = R0 + (size_t)15 * 1024 * 1024;

    const int M = 4096;
    dim3 blk(256);

    // 1. prep: xb (R2), WqkvT, W1T (R3), WoT — one launch
    prep_fused<<<dim3(4096 + 768 + 1024 + 256), blk, 0, stream>>>(
        x, R2, Wqkv, WqkvT, W1, R3, Wo, WoT);
    // 2. qkv: Q(pre-scaled)/K -> R0, V transposed -> VT (R1); m97-structure
    gemm128<1><<<dim3(24, 32), blk, 0, stream>>>(R2, WqkvT, bqkv, R0, R1, M, 3072, 1024, 0);
    // 3. attention -> av (R2; xb dead)
    attn_mfma<<<dim3(512), dim3(512), 0, stream>>>(R0, R1, R2);
    // 4. attn_out = av @ Wo + bo -> R1 (VT dead)
    gemm_bt_n64<<<dim3(16, 32), blk, 0, stream>>>(R2, WoT, bo, R1, M, 1024, 1024, 0);
    // 5. h = LN1(attn_out + x) -> R1 in-place  +  W2T -> R2 (av dead) — fused
    ln1_w2t_fused<<<dim3(4096 + 1024), blk, 0, stream>>>(R1, x, g1, be1, R1, W2, R2);
    // 6. ffn1 = relu(h @ W1 + b1) -> R0 (qkv/WqkvT/WoT dead); m97-structure
    gemm128<0><<<dim3(32, 32), blk, 0, stream>>>(R1, R3, b1, R0, nullptr, M, 4096, 1024, 1);
    // 7. ffn2 = ffn1 @ W2 + b2 -> R3 (W1T dead)
    gemm_bt_n64<<<dim3(16, 32), blk, 0, stream>>>(R0, R2, b2, R3, M, 1024, 4096, 0);
    // 8. out = LN2(ffn2 + h)
    ln_fused<0, 1><<<dim3(4096), blk, 0, stream>>>(R3, R1, g2, be2, out);
}

// Round 12
// 337.951 us; speedup vs baseline: 1.0493x; 1.0493x over previous
//
#include <hip/hip_runtime.h>
#include <stdint.h>

typedef float v4f __attribute__((ext_vector_type(4)));
typedef __bf16 v8bf __attribute__((ext_vector_type(8)));
typedef __bf16 v4bf __attribute__((ext_vector_type(4)));
typedef unsigned short v8us __attribute__((ext_vector_type(8)));
typedef unsigned short v4us __attribute__((ext_vector_type(4)));

__device__ __forceinline__ float b2f(unsigned short u) {
    union { float f; uint32_t i; } x; x.i = ((uint32_t)u) << 16; return x.f;
}
__device__ __forceinline__ unsigned short f2b(float f) {
    union { float f; uint32_t u; } x; x.f = f;
    uint32_t r = x.u + 0x7fffu + ((x.u >> 16) & 1u);
    return (unsigned short)(r >> 16);
}

// async global->LDS, 16B/lane. LDS dst must be wave-uniform; HW adds lane*16.
__device__ __forceinline__ void gload16(const unsigned short* g, unsigned short* l) {
    __builtin_amdgcn_global_load_lds(
        (const __attribute__((address_space(1))) void*)g,
        (__attribute__((address_space(3))) void*)l,
        16, 0, 0);
}

// ---------------------------------------------------------------------------
// Transpose tile body: W[K][N] fp32 -> WT[N][K] bf16, one 64x64 tile.
// ---------------------------------------------------------------------------
__device__ __forceinline__ void transpose_tile(
    const float* __restrict__ W, unsigned short* __restrict__ WT,
    int K, int N, int kb, int nb, int tid)
{
    __shared__ unsigned short t[64][65];
    const int r = tid >> 4, c4 = (tid & 15) * 4;
    #pragma unroll
    for (int i = 0; i < 4; ++i) {
        int k = r + i * 16;
        float4 v = *(const float4*)&W[(size_t)(kb + k) * N + nb + c4];
        t[c4 + 0][k] = f2b(v.x);
        t[c4 + 1][k] = f2b(v.y);
        t[c4 + 2][k] = f2b(v.z);
        t[c4 + 3][k] = f2b(v.w);
    }
    __syncthreads();
    #pragma unroll
    for (int i = 0; i < 4; ++i) {
        int n = r + i * 16;
        v4us o = {t[n][c4], t[n][c4 + 1], t[n][c4 + 2], t[n][c4 + 3]};
        *(v4us*)&WT[(size_t)(nb + n) * K + kb + c4] = o;
    }
}

// ---------------------------------------------------------------------------
// r21 prep_fused: x convert (4096 blocks) + WqkvT (768) + W1T (1024) +
// WoT (256) in ONE launch. Block-uniform branch.
// ---------------------------------------------------------------------------
__global__ __launch_bounds__(256) void prep_fused(
    const float* __restrict__ x, unsigned short* __restrict__ xb,
    const float* __restrict__ Wqkv, unsigned short* __restrict__ WqkvT,
    const float* __restrict__ W1, unsigned short* __restrict__ W1T,
    const float* __restrict__ Wo, unsigned short* __restrict__ WoT)
{
    const int b = blockIdx.x, tid = threadIdx.x;
    if (b < 4096) {
        int i = (b * 256 + tid) * 4;
        float4 v = *(const float4*)&x[i];
        v4us o = {f2b(v.x), f2b(v.y), f2b(v.z), f2b(v.w)};
        *(v4us*)&xb[i] = o;
    } else if (b < 4096 + 768) {
        int lb = b - 4096;                       // Wqkv: 48 x 16 tiles
        transpose_tile(Wqkv, WqkvT, 1024, 3072, (lb / 48) * 64, (lb % 48) * 64, tid);
    } else if (b < 4096 + 768 + 1024) {
        int lb = b - 4096 - 768;                 // W1: 64 x 16 tiles
        transpose_tile(W1, W1T, 1024, 4096, (lb / 64) * 64, (lb % 64) * 64, tid);
    } else {
        int lb = b - 4096 - 768 - 1024;          // Wo: 16 x 16 tiles
        transpose_tile(Wo, WoT, 1024, 1024, (lb / 16) * 64, (lb % 16) * 64, tid);
    }
}

// ---------------------------------------------------------------------------
// XCD-locality swizzle for GEMM grids (validated r14). MB must be %8.
// ---------------------------------------------------------------------------
__device__ __forceinline__ void xcd_swizzle(int& bm, int& bn) {
    int NB = gridDim.x, MB = gridDim.y;
    int flat = blockIdx.x + NB * blockIdx.y;
    int xcd = flat & 7, j = flat >> 3;
    int MBand = MB >> 3;
    bm = xcd * MBand + (j % MBand);
    bn = j / MBand;
}

// ---------------------------------------------------------------------------
// 128x64-tile GEMM for narrow-N (N=1024), BK=64. r20: depth-2 prefetch +
// single-barrier dbuf with STATIC register indexing (rule #20). K %128.
// ---------------------------------------------------------------------------
__global__ __launch_bounds__(256) void gemm_bt_n64(
    const unsigned short* __restrict__ A, const unsigned short* __restrict__ BT,
    const float* __restrict__ bias, unsigned short* __restrict__ C,
    int M, int N, int K, int relu)
{
    __shared__ __align__(16) unsigned short sA0[2][128 * 32];
    __shared__ __align__(16) unsigned short sB0[2][64 * 32];
    __shared__ __align__(16) unsigned short sA1[2][128 * 32];
    __shared__ __align__(16) unsigned short sB1[2][64 * 32];
    const int tid  = threadIdx.x;
    const int wave = tid >> 6, lane = tid & 63;
    const int wm = wave >> 1, wn = wave & 1;
    const int quad = lane >> 4, l16 = lane & 15;
    int bm, bn;
    xcd_swizzle(bm, bn);

    const int srow = lane >> 2, scol = (lane & 3) * 8;
    const unsigned short* ga0 = A  + (size_t)(bm * 128 + (wave * 2 + 0) * 16 + srow) * K + scol;
    const unsigned short* ga1 = A  + (size_t)(bm * 128 + (wave * 2 + 1) * 16 + srow) * K + scol;
    const unsigned short* gb0 = BT + (size_t)(bn * 64 + wave * 16 + srow) * K + scol;
    const int oa0 = (wave * 2 + 0) * 512 + lane * 8;
    const int oa1 = (wave * 2 + 1) * 512 + lane * 8;
    const int ob  = wave * 512 + lane * 8;

    v8us aR0[2][2], bR0[2], aR1[2][2], bR1[2];
    #pragma unroll
    for (int c = 0; c < 2; ++c) {
        aR0[c][0] = *(const v8us*)(ga0 + c * 32);
        aR0[c][1] = *(const v8us*)(ga1 + c * 32);
        bR0[c]    = *(const v8us*)(gb0 + c * 32);
        aR1[c][0] = *(const v8us*)(ga0 + 64 + c * 32);
        aR1[c][1] = *(const v8us*)(ga1 + 64 + c * 32);
        bR1[c]    = *(const v8us*)(gb0 + 64 + c * 32);
    }

    v4f acc[4][2];
    #pragma unroll
    for (int i = 0; i < 4; ++i)
        #pragma unroll
        for (int j = 0; j < 2; ++j)
            acc[i][j] = (v4f){0.f, 0.f, 0.f, 0.f};

    for (int kt = 0; kt < K; kt += 128) {
        // ---- half 0 ----
        #pragma unroll
        for (int c = 0; c < 2; ++c) {
            *(v8us*)&sA0[c][oa0] = aR0[c][0];
            *(v8us*)&sA0[c][oa1] = aR0[c][1];
            *(v8us*)&sB0[c][ob]  = bR0[c];
        }
        __syncthreads();
        if (kt + 128 < K) {
            const int kn = kt + 128;
            #pragma unroll
            for (int c = 0; c < 2; ++c) {
                aR0[c][0] = *(const v8us*)(ga0 + kn + c * 32);
                aR0[c][1] = *(const v8us*)(ga1 + kn + c * 32);
                bR0[c]    = *(const v8us*)(gb0 + kn + c * 32);
            }
        }
        #pragma unroll
        for (int c = 0; c < 2; ++c) {
            v8bf af[4], bfr[2];
            #pragma unroll
            for (int mt = 0; mt < 4; ++mt)
                af[mt] = *(const v8bf*)&sA0[c][(wm * 64 + mt * 16 + l16) * 32 + quad * 8];
            #pragma unroll
            for (int nt = 0; nt < 2; ++nt)
                bfr[nt] = *(const v8bf*)&sB0[c][(wn * 32 + nt * 16 + l16) * 32 + quad * 8];
            #pragma unroll
            for (int mt = 0; mt < 4; ++mt)
                #pragma unroll
                for (int nt = 0; nt < 2; ++nt)
                    acc[mt][nt] = __builtin_amdgcn_mfma_f32_16x16x32_bf16(
                        af[mt], bfr[nt], acc[mt][nt], 0, 0, 0);
        }

        // ---- half 1 ----
        #pragma unroll
        for (int c = 0; c < 2; ++c) {
            *(v8us*)&sA1[c][oa0] = aR1[c][0];
            *(v8us*)&sA1[c][oa1] = aR1[c][1];
            *(v8us*)&sB1[c][ob]  = bR1[c];
        }
        __syncthreads();
        if (kt + 192 < K) {
            const int kn = kt + 192;
            #pragma unroll
            for (int c = 0; c < 2; ++c) {
                aR1[c][0] = *(const v8us*)(ga0 + kn + c * 32);
                aR1[c][1] = *(const v8us*)(ga1 + kn + c * 32);
                bR1[c]    = *(const v8us*)(gb0 + kn + c * 32);
            }
        }
        #pragma unroll
        for (int c = 0; c < 2; ++c) {
            v8bf af[4], bfr[2];
            #pragma unroll
            for (int mt = 0; mt < 4; ++mt)
                af[mt] = *(const v8bf*)&sA1[c][(wm * 64 + mt * 16 + l16) * 32 + quad * 8];
            #pragma unroll
            for (int nt = 0; nt < 2; ++nt)
                bfr[nt] = *(const v8bf*)&sB1[c][(wn * 32 + nt * 16 + l16) * 32 + quad * 8];
            #pragma unroll
            for (int mt = 0; mt < 4; ++mt)
                #pragma unroll
                for (int nt = 0; nt < 2; ++nt)
                    acc[mt][nt] = __builtin_amdgcn_mfma_f32_16x16x32_bf16(
                        af[mt], bfr[nt], acc[mt][nt], 0, 0, 0);
        }
    }

    #pragma unroll
    for (int mt = 0; mt < 4; ++mt) {
        #pragma unroll
        for (int nt = 0; nt < 2; ++nt) {
            int col = bn * 64 + wn * 32 + nt * 16 + l16;
            float bv = bias ? bias[col] : 0.f;
            #pragma unroll
            for (int r = 0; r < 4; ++r) {
                int row = bm * 128 + wm * 64 + mt * 16 + quad * 4 + r;
                float v = acc[mt][nt][r] + bv;
                if (relu) v = fmaxf(v, 0.f);
                C[(size_t)row * N + col] = f2b(v);
            }
        }
    }
}

// ---------------------------------------------------------------------------
// gemm256 (r21 known-good, the measured local optimum among verified
// structures): 256x256 tile, 512 thr / 8 waves (2M x 4N), BK=64, 2-phase
// global_load_lds + st_16x32 swizzle. SPLIT_V templated epilogue for QKV.
// grid: (N/256, M/256), MB%8. (r22 counted-vmcnt and r24 single-buffer
// 128^2 both regressed vs this at K=1024.)
// ---------------------------------------------------------------------------
template<int SPLIT_V>
__global__ __launch_bounds__(512) void gemm256(
    const unsigned short* __restrict__ A, const unsigned short* __restrict__ BT,
    const float* __restrict__ bias, unsigned short* __restrict__ C,
    unsigned short* __restrict__ VT, int M, int N, int K, int relu)
{
    __shared__ __align__(16) unsigned short sA[2][256 * 64];
    __shared__ __align__(16) unsigned short sB[2][256 * 64];
    const int tid  = threadIdx.x;
    const int wave = tid >> 6, lane = tid & 63;
    const int wm = wave >> 2, wn = wave & 3;     // 2M x 4N wave grid
    const int quad = lane >> 4, l16 = lane & 15;
    int bm, bn;
    xcd_swizzle(bm, bn);

    const int srow = lane >> 3;
    const int scol = ((lane & 7) * 8) ^ ((lane & 32) ? 16 : 0);
    size_t aoff[4], boff[4];
    #pragma unroll
    for (int j = 0; j < 4; ++j) {
        int r = wave * 32 + j * 8 + srow;
        aoff[j] = (size_t)(bm * 256 + r) * K + scol;
        boff[j] = (size_t)(bn * 256 + r) * K + scol;
    }
    const int lds0 = wave * 32 * 64;   // shorts; + j*512 per issue

    // ds_read swizzle: logical k-col quad*8 -> phys ^16 iff row&4 (= l16&4)
    const int ksw = (quad * 8) ^ ((l16 & 4) ? 16 : 0);

    v4f acc[8][4];
    #pragma unroll
    for (int i = 0; i < 8; ++i)
        #pragma unroll
        for (int j = 0; j < 4; ++j)
            acc[i][j] = (v4f){0.f, 0.f, 0.f, 0.f};

    const int NT = K >> 6;
    #pragma unroll
    for (int j = 0; j < 4; ++j) {
        gload16(A  + aoff[j], &sA[0][lds0 + j * 512]);
        gload16(BT + boff[j], &sB[0][lds0 + j * 512]);
    }
    __syncthreads();

    for (int t = 0; t < NT; ++t) {
        const int buf = t & 1;
        if (t + 1 < NT) {
            const int ktn = (t + 1) << 6;
            #pragma unroll
            for (int j = 0; j < 4; ++j) {
                gload16(A  + aoff[j] + ktn, &sA[buf ^ 1][lds0 + j * 512]);
                gload16(BT + boff[j] + ktn, &sB[buf ^ 1][lds0 + j * 512]);
            }
        }

        v8bf bfr[4][2];
        #pragma unroll
        for (int nt2 = 0; nt2 < 4; ++nt2)
            #pragma unroll
            for (int kc = 0; kc < 2; ++kc)
                bfr[nt2][kc] = *(const v8bf*)&sB[buf][
                    (wn * 64 + nt2 * 16 + l16) * 64 + kc * 32 + ksw];
        #pragma unroll
        for (int mq = 0; mq < 2; ++mq) {
            v8bf af[4][2];
            #pragma unroll
            for (int mt2 = 0; mt2 < 4; ++mt2)
                #pragma unroll
                for (int kc = 0; kc < 2; ++kc)
                    af[mt2][kc] = *(const v8bf*)&sA[buf][
                        (wm * 128 + mq * 64 + mt2 * 16 + l16) * 64 + kc * 32 + ksw];
            #pragma unroll
            for (int mt2 = 0; mt2 < 4; ++mt2)
                #pragma unroll
                for (int nt2 = 0; nt2 < 4; ++nt2)
                    #pragma unroll
                    for (int kc = 0; kc < 2; ++kc)
                        acc[mq * 4 + mt2][nt2] =
                            __builtin_amdgcn_mfma_f32_16x16x32_bf16(
                                af[mt2][kc], bfr[nt2][kc],
                                acc[mq * 4 + mt2][nt2], 0, 0, 0);
        }
        __syncthreads();   // drains vmcnt (tile t+1 landed) + lgkm (reads done)
    }

    #pragma unroll
    for (int mt = 0; mt < 8; ++mt) {
        int row = bm * 256 + wm * 128 + mt * 16 + quad * 4;
        #pragma unroll
        for (int nt = 0; nt < 4; ++nt) {
            int c0 = bn * 256 + wn * 64 + nt * 16;
            int col = c0 + l16;
            float bv = bias ? bias[col] : 0.f;
            if (SPLIT_V && (c0 % 192) >= 128) {
                int hh = c0 / 192;
                int d  = (c0 % 192) - 128 + l16;
                int bb = row >> 11;
                int s  = row & 2047;
                v4us st;
                #pragma unroll
                for (int r = 0; r < 4; ++r)
                    st[r] = f2b(acc[mt][nt][r] + bv);
                *(v4us*)&VT[((size_t)(bb * 16 + hh) * 64 + d) * 2048 + s] = st;
            } else {
                float qs = (SPLIT_V && (c0 % 192) < 64) ? 0.18033688f : 1.0f;
                #pragma unroll
                for (int r = 0; r < 4; ++r) {
                    float v = (acc[mt][nt][r] + bv) * qs;
                    if (relu) v = fmaxf(v, 0.f);
                    C[(size_t)(row + r) * N + col] = f2b(v);
                }
            }
        }
    }
}

// ---------------------------------------------------------------------------
// MFMA flash attention v11 (r18): 512 threads / 8 waves, 16 q/wave, grid 512,
// single-barrier double-buffered K/V LDS. LDS 55296 B -> 2 blocks/CU.
// ---------------------------------------------------------------------------
__global__ __launch_bounds__(512) void attn_mfma(
    const unsigned short* __restrict__ qkv, const unsigned short* __restrict__ VT,
    unsigned short* __restrict__ av)
{
    __shared__ __align__(16) unsigned short sK[2][64 * 72];
    __shared__ __align__(16) unsigned short sVT[2][64 * 72];
    __shared__ __align__(16) unsigned short sP[8][16 * 72];
    const int tid  = threadIdx.x;
    const int wave = tid >> 6, lane = tid & 63;
    const int quad = lane >> 4, l16 = lane & 15;
    const int blk = blockIdx.x;
    const int xcd = blk & 7, local = blk >> 3;
    const int bh = xcd * 4 + (local & 3);     // all q-blocks of a bh on one XCD
    const int qb = local >> 2;                // [0,16): 128-row q-block
    const int h = bh & 15, b = bh >> 4;
    const int row0 = b * 2048;
    const int qbase = row0 + qb * 128 + wave * 16;
    const size_t qoff = (size_t)h * 192;
    const size_t koff = qoff + 64;

    v8bf qf[2];
    #pragma unroll
    for (int kc = 0; kc < 2; ++kc)
        qf[kc] = *(const v8bf*)&qkv[(size_t)(qbase + l16) * 3072
                                    + qoff + kc * 32 + quad * 8];

    v4f o[4];
    #pragma unroll
    for (int dt = 0; dt < 4; ++dt)
        o[dt] = (v4f){0.f, 0.f, 0.f, 0.f};
    float ll = 0.f;

    // staging: 512 threads cover 64x64 K tile and 64x64 V tile, 1 v8us each
    const int k_key = tid >> 3, k_oct = (tid & 7) * 8;
    const unsigned short* gK = qkv + (size_t)(row0 + k_key) * 3072 + koff + k_oct;
    const unsigned short* gV = VT + ((size_t)bh * 64 + k_key) * 2048 + k_oct;
    const size_t stepK = (size_t)64 * 3072;
    const size_t stepV = 64;

    v8us kreg = *(const v8us*)gK;
    v8us vreg = *(const v8us*)gV;
    gK += stepK; gV += stepV;

    for (int kt = 0; kt < 32; ++kt) {
        const int cur = kt & 1;
        *(v8us*)&sK[cur][k_key * 72 + k_oct]  = kreg;
        *(v8us*)&sVT[cur][k_key * 72 + k_oct] = vreg;
        __syncthreads();
        if (kt < 31) {
            kreg = *(const v8us*)gK;
            vreg = *(const v8us*)gV;
            gK += stepK; gV += stepV;
        }

        v4f sc[4];
        #pragma unroll
        for (int kk = 0; kk < 4; ++kk) {
            sc[kk] = (v4f){0.f, 0.f, 0.f, 0.f};
            #pragma unroll
            for (int kc = 0; kc < 2; ++kc) {
                v8bf ak = *(const v8bf*)&sK[cur][(kk * 16 + l16) * 72 + kc * 32 + quad * 8];
                sc[kk] = __builtin_amdgcn_mfma_f32_16x16x32_bf16(
                    ak, qf[kc], sc[kk], 0, 0, 0);
            }
        }

        float ps = 0.f;
        #pragma unroll
        for (int kk = 0; kk < 4; ++kk) {
            v4bf pk;
            #pragma unroll
            for (int rr = 0; rr < 4; ++rr) {
                float p = __builtin_amdgcn_exp2f(sc[kk][rr]);
                ps += p;
                pk[rr] = (__bf16)p;
            }
            *(v4bf*)&sP[wave][l16 * 72 + kk * 16 + quad * 4] = pk;
        }
        ll += ps;

        __asm__ volatile("s_waitcnt lgkmcnt(0)" ::: "memory");

        #pragma unroll
        for (int c = 0; c < 2; ++c) {
            union { v8bf v; v8us u; } u;
            u.u = *(const v8us*)&sP[wave][l16 * 72 + c * 32 + quad * 8];
            v8bf pb = u.v;
            #pragma unroll
            for (int dt = 0; dt < 4; ++dt) {
                v8bf va = *(const v8bf*)&sVT[cur][(dt * 16 + l16) * 72 + c * 32 + quad * 8];
                o[dt] = __builtin_amdgcn_mfma_f32_16x16x32_bf16(
                    va, pb, o[dt], 0, 0, 0);
            }
        }
    }

    float l = ll;
    l += __shfl_xor(l, 16, 64);
    l += __shfl_xor(l, 32, 64);
    float inv = 1.f / l;
    int qrow = qbase + l16;
    #pragma unroll
    for (int dt = 0; dt < 4; ++dt) {
        v4bf st;
        #pragma unroll
        for (int rr = 0; rr < 4; ++rr)
            st[rr] = (__bf16)(o[dt][rr] * inv);
        *(v4bf*)&av[(size_t)qrow * 1024 + h * 64 + dt * 16 + quad * 4] = st;
    }
}

// ---------------------------------------------------------------------------
// LN1 body (residual f32, out bf16, in-place safe).
// ---------------------------------------------------------------------------
__device__ __forceinline__ void ln_row_f32res(
    const unsigned short* __restrict__ a, const float* __restrict__ resid,
    const float* __restrict__ gamma, const float* __restrict__ beta,
    unsigned short* __restrict__ outp, int row, int tid)
{
    const size_t base = (size_t)row * 1024;
    const int c0 = tid * 4;
    ushort4 avv = *(const ushort4*)&a[base + c0];
    float4 rv = *(const float4*)&resid[base + c0];
    float y[4];
    y[0] = b2f(avv.x) + rv.x;
    y[1] = b2f(avv.y) + rv.y;
    y[2] = b2f(avv.z) + rv.z;
    y[3] = b2f(avv.w) + rv.w;
    float s  = y[0] + y[1] + y[2] + y[3];
    float ss = y[0]*y[0] + y[1]*y[1] + y[2]*y[2] + y[3]*y[3];
    #pragma unroll
    for (int off = 32; off; off >>= 1) {
        s  += __shfl_xor(s, off, 64);
        ss += __shfl_xor(ss, off, 64);
    }
    __shared__ float red[8];
    int wave = tid >> 6, lane = tid & 63;
    if (lane == 0) { red[wave] = s; red[4 + wave] = ss; }
    __syncthreads();
    s  = red[0] + red[1] + red[2] + red[3];
    ss = red[4] + red[5] + red[6] + red[7];
    float mean = s * (1.f / 1024.f);
    float var  = ss * (1.f / 1024.f) - mean * mean;
    float rstd = rsqrtf(var + 1e-5f);
    float4 gv = *(const float4*)&gamma[c0];
    float4 bv = *(const float4*)&beta[c0];
    ushort4 ov;
    ov.x = f2b(gv.x * (y[0] - mean) * rstd + bv.x);
    ov.y = f2b(gv.y * (y[1] - mean) * rstd + bv.y);
    ov.z = f2b(gv.z * (y[2] - mean) * rstd + bv.z);
    ov.w = f2b(gv.w * (y[3] - mean) * rstd + bv.w);
    *(ushort4*)&outp[base + c0] = ov;
}

// ---------------------------------------------------------------------------
// r23: LN1 (4096 rows) + W2T transpose (1024 tiles) fused into one launch.
// ---------------------------------------------------------------------------
__global__ __launch_bounds__(256) void ln1_w2t_fused(
    const unsigned short* __restrict__ a, const float* __restrict__ x,
    const float* __restrict__ gamma, const float* __restrict__ beta,
    unsigned short* __restrict__ h_out,
    const float* __restrict__ W2, unsigned short* __restrict__ W2T)
{
    const int b = blockIdx.x, tid = threadIdx.x;
    if (b < 4096) {
        ln_row_f32res(a, x, gamma, beta, h_out, b, tid);
    } else {
        int lb = b - 4096;                       // W2: [4096][1024] -> 64x16 tiles
        transpose_tile(W2, W2T, 4096, 1024, (lb / 16) * 64, (lb % 16) * 64, tid);
    }
}

// ---------------------------------------------------------------------------
// Fused residual-add + LayerNorm (standalone, used for LN2).
// ---------------------------------------------------------------------------
template<int RES_F32, int OUT_F32>
__global__ __launch_bounds__(256) void ln_fused(
    const unsigned short* __restrict__ a, const void* __restrict__ residv,
    const float* __restrict__ gamma, const float* __restrict__ beta,
    void* __restrict__ outv)
{
    const int row = blockIdx.x, tid = threadIdx.x;
    const size_t base = (size_t)row * 1024;
    const int c0 = tid * 4;
    ushort4 avv = *(const ushort4*)&a[base + c0];
    float y[4];
    if (RES_F32) {
        float4 rv = *(const float4*)((const float*)residv + base + c0);
        y[0] = b2f(avv.x) + rv.x;
        y[1] = b2f(avv.y) + rv.y;
        y[2] = b2f(avv.z) + rv.z;
        y[3] = b2f(avv.w) + rv.w;
    } else {
        ushort4 rv = *(const ushort4*)((const unsigned short*)residv + base + c0);
        y[0] = b2f(avv.x) + b2f(rv.x);
        y[1] = b2f(avv.y) + b2f(rv.y);
        y[2] = b2f(avv.z) + b2f(rv.z);
        y[3] = b2f(avv.w) + b2f(rv.w);
    }
    float s  = y[0] + y[1] + y[2] + y[3];
    float ss = y[0]*y[0] + y[1]*y[1] + y[2]*y[2] + y[3]*y[3];
    #pragma unroll
    for (int off = 32; off; off >>= 1) {
        s  += __shfl_xor(s, off, 64);
        ss += __shfl_xor(ss, off, 64);
    }
    __shared__ float red[8];
    int wave = tid >> 6, lane = tid & 63;
    if (lane == 0) { red[wave] = s; red[4 + wave] = ss; }
    __syncthreads();
    s  = red[0] + red[1] + red[2] + red[3];
    ss = red[4] + red[5] + red[6] + red[7];
    float mean = s * (1.f / 1024.f);
    float var  = ss * (1.f / 1024.f) - mean * mean;
    float rstd = rsqrtf(var + 1e-5f);
    float4 gv = *(const float4*)&gamma[c0];
    float4 bv = *(const float4*)&beta[c0];
    float r0 = gv.x * (y[0] - mean) * rstd + bv.x;
    float r1 = gv.y * (y[1] - mean) * rstd + bv.y;
    float r2 = gv.z * (y[2] - mean) * rstd + bv.z;
    float r3 = gv.w * (y[3] - mean) * rstd + bv.w;
    if (OUT_F32) {
        float4 ov = {r0, r1, r2, r3};
        *(float4*)((float*)outv + base + c0) = ov;
    } else {
        ushort4 ov;
        ov.x = f2b(r0); ov.y = f2b(r1); ov.z = f2b(r2); ov.w = f2b(r3);
        *(ushort4*)((unsigned short*)outv + base + c0) = ov;
    }
}

// ---------------------------------------------------------------------------
// Final pipeline (8 launches) — the measured best configuration (337-339us):
//  R0[0..12M): qkv Q/K -> ffn1(16M)
//  R0[12M..15M): WqkvT   R0[15M..16M): WoT
//  R1: VT -> attn_out -> h (LN1 in-place) -> residual for LN2
//  R2: xb -> av -> W2T
//  R3: W1T -> ffn2
// ---------------------------------------------------------------------------
extern "C" void kernel_launch(void* const* d_in, const int* in_sizes, int n_in,
                              void* d_out, int out_size, void* d_ws, size_t ws_size,
                              hipStream_t stream)
{
    (void)in_sizes; (void)n_in; (void)out_size; (void)ws_size;
    const float* x    = (const float*)d_in[0];
    const float* Wqkv = (const float*)d_in[1];
    const float* bqkv = (const float*)d_in[2];
    const float* Wo   = (const float*)d_in[3];
    const float* bo   = (const float*)d_in[4];
    const float* g1   = (const float*)d_in[5];
    const float* be1  = (const float*)d_in[6];
    const float* W1   = (const float*)d_in[7];
    const float* b1   = (const float*)d_in[8];
    const float* W2   = (const float*)d_in[9];
    const float* b2   = (const float*)d_in[10];
    const float* g2   = (const float*)d_in[11];
    const float* be2  = (const float*)d_in[12];
    float* out = (float*)d_out;

    unsigned short* R0 = (unsigned short*)d_ws;
    unsigned short* R1 = R0 + (size_t)16 * 1024 * 1024;
    unsigned short* R2 = R1 + (size_t)4 * 1024 * 1024;
    unsigned short* R3 = R2 + (size_t)4 * 1024 * 1024;
    unsigned short* WqkvT = R0 + (size_t)12 * 1024 * 1024;
    unsigned short* WoT   = R0 + (size_t)15 * 1024 * 1024;

    const int M = 4096;
    dim3 blk(256);

    // 1. prep: xb (R2), WqkvT, W1T (R3), WoT — one launch
    prep_fused<<<dim3(4096 + 768 + 1024 + 256), blk, 0, stream>>>(
        x, R2, Wqkv, WqkvT, W1, R3, Wo, WoT);
    // 2. qkv: Q(pre-scaled)/K -> R0, V transposed -> VT (R1)
    gemm256<1><<<dim3(12, 16), dim3(512), 0, stream>>>(R2, WqkvT, bqkv, R0, R1, M, 3072, 1024, 0);
    // 3. attention -> av (R2; xb dead)
    attn_mfma<<<dim3(512), dim3(512), 0, stream>>>(R0, R1, R2);
    // 4. attn_out = av @ Wo + bo -> R1 (VT dead)
    gemm_bt_n64<<<dim3(16, 32), blk, 0, stream>>>(R2, WoT, bo, R1, M, 1024, 1024, 0);
    // 5. h = LN1(attn_out + x) -> R1 in-place  +  W2T -> R2 (av dead) — fused
    ln1_w2t_fused<<<dim3(4096 + 1024), blk, 0, stream>>>(R1, x, g1, be1, R1, W2, R2);
    // 6. ffn1 = relu(h @ W1 + b1) -> R0 (qkv/WqkvT/WoT dead)
    gemm256<0><<<dim3(16, 16), dim3(512), 0, stream>>>(R1, R3, b1, R0, nullptr, M, 4096, 1024, 1);
    // 7. ffn2 = ffn1 @ W2 + b2 -> R3 (W1T dead)
    gemm_bt_n64<<<dim3(16, 32), blk, 0, stream>>>(R0, R2, b2, R3, M, 1024, 4096, 0);
    // 8. out = LN2(ffn2 + h)
    ln_fused<0, 1><<<dim3(4096), blk, 0, stream>>>(R3, R1, g2, be2, out);
}

// Round 13
// 331.679 us; speedup vs baseline: 1.0692x; 1.0189x over previous
//
#include <hip/hip_runtime.h>
#include <stdint.h>

typedef float v4f __attribute__((ext_vector_type(4)));
typedef __bf16 v8bf __attribute__((ext_vector_type(8)));
typedef __bf16 v4bf __attribute__((ext_vector_type(4)));
typedef unsigned short v8us __attribute__((ext_vector_type(8)));
typedef unsigned short v4us __attribute__((ext_vector_type(4)));

__device__ __forceinline__ float b2f(unsigned short u) {
    union { float f; uint32_t i; } x; x.i = ((uint32_t)u) << 16; return x.f;
}
__device__ __forceinline__ unsigned short f2b(float f) {
    union { float f; uint32_t u; } x; x.f = f;
    uint32_t r = x.u + 0x7fffu + ((x.u >> 16) & 1u);
    return (unsigned short)(r >> 16);
}

// async global->LDS, 16B/lane. LDS dst must be wave-uniform; HW adds lane*16.
__device__ __forceinline__ void gload16(const unsigned short* g, unsigned short* l) {
    __builtin_amdgcn_global_load_lds(
        (const __attribute__((address_space(1))) void*)g,
        (__attribute__((address_space(3))) void*)l,
        16, 0, 0);
}

// ---------------------------------------------------------------------------
// Transpose tile body: W[K][N] fp32 -> WT[N][K] bf16, one 64x64 tile.
// ---------------------------------------------------------------------------
__device__ __forceinline__ void transpose_tile(
    const float* __restrict__ W, unsigned short* __restrict__ WT,
    int K, int N, int kb, int nb, int tid)
{
    __shared__ unsigned short t[64][65];
    const int r = tid >> 4, c4 = (tid & 15) * 4;
    #pragma unroll
    for (int i = 0; i < 4; ++i) {
        int k = r + i * 16;
        float4 v = *(const float4*)&W[(size_t)(kb + k) * N + nb + c4];
        t[c4 + 0][k] = f2b(v.x);
        t[c4 + 1][k] = f2b(v.y);
        t[c4 + 2][k] = f2b(v.z);
        t[c4 + 3][k] = f2b(v.w);
    }
    __syncthreads();
    #pragma unroll
    for (int i = 0; i < 4; ++i) {
        int n = r + i * 16;
        v4us o = {t[n][c4], t[n][c4 + 1], t[n][c4 + 2], t[n][c4 + 3]};
        *(v4us*)&WT[(size_t)(nb + n) * K + kb + c4] = o;
    }
}

// ---------------------------------------------------------------------------
// r21 prep_fused: x convert (4096 blocks) + WqkvT (768) + W1T (1024) +
// WoT (256) in ONE launch. Block-uniform branch.
// ---------------------------------------------------------------------------
__global__ __launch_bounds__(256) void prep_fused(
    const float* __restrict__ x, unsigned short* __restrict__ xb,
    const float* __restrict__ Wqkv, unsigned short* __restrict__ WqkvT,
    const float* __restrict__ W1, unsigned short* __restrict__ W1T,
    const float* __restrict__ Wo, unsigned short* __restrict__ WoT)
{
    const int b = blockIdx.x, tid = threadIdx.x;
    if (b < 4096) {
        int i = (b * 256 + tid) * 4;
        float4 v = *(const float4*)&x[i];
        v4us o = {f2b(v.x), f2b(v.y), f2b(v.z), f2b(v.w)};
        *(v4us*)&xb[i] = o;
    } else if (b < 4096 + 768) {
        int lb = b - 4096;                       // Wqkv: 48 x 16 tiles
        transpose_tile(Wqkv, WqkvT, 1024, 3072, (lb / 48) * 64, (lb % 48) * 64, tid);
    } else if (b < 4096 + 768 + 1024) {
        int lb = b - 4096 - 768;                 // W1: 64 x 16 tiles
        transpose_tile(W1, W1T, 1024, 4096, (lb / 64) * 64, (lb % 64) * 64, tid);
    } else {
        int lb = b - 4096 - 768 - 1024;          // Wo: 16 x 16 tiles
        transpose_tile(Wo, WoT, 1024, 1024, (lb / 16) * 64, (lb % 16) * 64, tid);
    }
}

// ---------------------------------------------------------------------------
// XCD-locality swizzle for GEMM grids (validated r14). MB must be %8.
// ---------------------------------------------------------------------------
__device__ __forceinline__ void xcd_swizzle(int& bm, int& bn) {
    int NB = gridDim.x, MB = gridDim.y;
    int flat = blockIdx.x + NB * blockIdx.y;
    int xcd = flat & 7, j = flat >> 3;
    int MBand = MB >> 3;
    bm = xcd * MBand + (j % MBand);
    bn = j / MBand;
}

// ---------------------------------------------------------------------------
// 128x64-tile GEMM for narrow-N (N=1024), BK=64. r20: depth-2 prefetch +
// single-barrier dbuf with STATIC register indexing (rule #20). K %128.
// ---------------------------------------------------------------------------
__global__ __launch_bounds__(256) void gemm_bt_n64(
    const unsigned short* __restrict__ A, const unsigned short* __restrict__ BT,
    const float* __restrict__ bias, unsigned short* __restrict__ C,
    int M, int N, int K, int relu)
{
    __shared__ __align__(16) unsigned short sA0[2][128 * 32];
    __shared__ __align__(16) unsigned short sB0[2][64 * 32];
    __shared__ __align__(16) unsigned short sA1[2][128 * 32];
    __shared__ __align__(16) unsigned short sB1[2][64 * 32];
    const int tid  = threadIdx.x;
    const int wave = tid >> 6, lane = tid & 63;
    const int wm = wave >> 1, wn = wave & 1;
    const int quad = lane >> 4, l16 = lane & 15;
    int bm, bn;
    xcd_swizzle(bm, bn);

    const int srow = lane >> 2, scol = (lane & 3) * 8;
    const unsigned short* ga0 = A  + (size_t)(bm * 128 + (wave * 2 + 0) * 16 + srow) * K + scol;
    const unsigned short* ga1 = A  + (size_t)(bm * 128 + (wave * 2 + 1) * 16 + srow) * K + scol;
    const unsigned short* gb0 = BT + (size_t)(bn * 64 + wave * 16 + srow) * K + scol;
    const int oa0 = (wave * 2 + 0) * 512 + lane * 8;
    const int oa1 = (wave * 2 + 1) * 512 + lane * 8;
    const int ob  = wave * 512 + lane * 8;

    v8us aR0[2][2], bR0[2], aR1[2][2], bR1[2];
    #pragma unroll
    for (int c = 0; c < 2; ++c) {
        aR0[c][0] = *(const v8us*)(ga0 + c * 32);
        aR0[c][1] = *(const v8us*)(ga1 + c * 32);
        bR0[c]    = *(const v8us*)(gb0 + c * 32);
        aR1[c][0] = *(const v8us*)(ga0 + 64 + c * 32);
        aR1[c][1] = *(const v8us*)(ga1 + 64 + c * 32);
        bR1[c]    = *(const v8us*)(gb0 + 64 + c * 32);
    }

    v4f acc[4][2];
    #pragma unroll
    for (int i = 0; i < 4; ++i)
        #pragma unroll
        for (int j = 0; j < 2; ++j)
            acc[i][j] = (v4f){0.f, 0.f, 0.f, 0.f};

    for (int kt = 0; kt < K; kt += 128) {
        // ---- half 0 ----
        #pragma unroll
        for (int c = 0; c < 2; ++c) {
            *(v8us*)&sA0[c][oa0] = aR0[c][0];
            *(v8us*)&sA0[c][oa1] = aR0[c][1];
            *(v8us*)&sB0[c][ob]  = bR0[c];
        }
        __syncthreads();
        if (kt + 128 < K) {
            const int kn = kt + 128;
            #pragma unroll
            for (int c = 0; c < 2; ++c) {
                aR0[c][0] = *(const v8us*)(ga0 + kn + c * 32);
                aR0[c][1] = *(const v8us*)(ga1 + kn + c * 32);
                bR0[c]    = *(const v8us*)(gb0 + kn + c * 32);
            }
        }
        #pragma unroll
        for (int c = 0; c < 2; ++c) {
            v8bf af[4], bfr[2];
            #pragma unroll
            for (int mt = 0; mt < 4; ++mt)
                af[mt] = *(const v8bf*)&sA0[c][(wm * 64 + mt * 16 + l16) * 32 + quad * 8];
            #pragma unroll
            for (int nt = 0; nt < 2; ++nt)
                bfr[nt] = *(const v8bf*)&sB0[c][(wn * 32 + nt * 16 + l16) * 32 + quad * 8];
            #pragma unroll
            for (int mt = 0; mt < 4; ++mt)
                #pragma unroll
                for (int nt = 0; nt < 2; ++nt)
                    acc[mt][nt] = __builtin_amdgcn_mfma_f32_16x16x32_bf16(
                        af[mt], bfr[nt], acc[mt][nt], 0, 0, 0);
        }

        // ---- half 1 ----
        #pragma unroll
        for (int c = 0; c < 2; ++c) {
            *(v8us*)&sA1[c][oa0] = aR1[c][0];
            *(v8us*)&sA1[c][oa1] = aR1[c][1];
            *(v8us*)&sB1[c][ob]  = bR1[c];
        }
        __syncthreads();
        if (kt + 192 < K) {
            const int kn = kt + 192;
            #pragma unroll
            for (int c = 0; c < 2; ++c) {
                aR1[c][0] = *(const v8us*)(ga0 + kn + c * 32);
                aR1[c][1] = *(const v8us*)(ga1 + kn + c * 32);
                bR1[c]    = *(const v8us*)(gb0 + kn + c * 32);
            }
        }
        #pragma unroll
        for (int c = 0; c < 2; ++c) {
            v8bf af[4], bfr[2];
            #pragma unroll
            for (int mt = 0; mt < 4; ++mt)
                af[mt] = *(const v8bf*)&sA1[c][(wm * 64 + mt * 16 + l16) * 32 + quad * 8];
            #pragma unroll
            for (int nt = 0; nt < 2; ++nt)
                bfr[nt] = *(const v8bf*)&sB1[c][(wn * 32 + nt * 16 + l16) * 32 + quad * 8];
            #pragma unroll
            for (int mt = 0; mt < 4; ++mt)
                #pragma unroll
                for (int nt = 0; nt < 2; ++nt)
                    acc[mt][nt] = __builtin_amdgcn_mfma_f32_16x16x32_bf16(
                        af[mt], bfr[nt], acc[mt][nt], 0, 0, 0);
        }
    }

    #pragma unroll
    for (int mt = 0; mt < 4; ++mt) {
        #pragma unroll
        for (int nt = 0; nt < 2; ++nt) {
            int col = bn * 64 + wn * 32 + nt * 16 + l16;
            float bv = bias ? bias[col] : 0.f;
            #pragma unroll
            for (int r = 0; r < 4; ++r) {
                int row = bm * 128 + wm * 64 + mt * 16 + quad * 4 + r;
                float v = acc[mt][nt][r] + bv;
                if (relu) v = fmaxf(v, 0.f);
                C[(size_t)row * N + col] = f2b(v);
            }
        }
    }
}

// ---------------------------------------------------------------------------
// gemm256 (r21 structure), r25: templated on NF = N-fragments per wave.
// Tile = 256 x (NF*64). NF=4 -> 256x256 (FFN1, byte-identical to verified
// r21 kernel). NF=3 -> 256x192 (QKV): grid (3072/192, 4096/256) = (16,16) =
// 256 blocks = full CU coverage (the (12,16)=192-block 256-wide grid left
// 25% of CUs idle -> QKV was 64us for 25.8 GFLOP). BN=192 also aligns each
// block's N-range with one 192-col qkv head-triple. LDS: A 64KB + B NF*16KB.
// 2-phase global_load_lds + st_16x32 swizzle; 8 waves (2M x 4N).
// ---------------------------------------------------------------------------
template<int SPLIT_V, int NF>
__global__ __launch_bounds__(512) void gemm256(
    const unsigned short* __restrict__ A, const unsigned short* __restrict__ BT,
    const float* __restrict__ bias, unsigned short* __restrict__ C,
    unsigned short* __restrict__ VT, int M, int N, int K, int relu)
{
    constexpr int BN = NF * 64;              // 256 or 192
    constexpr int BROWS = BN / 8;            // B rows staged per wave
    __shared__ __align__(16) unsigned short sA[2][256 * 64];
    __shared__ __align__(16) unsigned short sB[2][BN * 64];
    const int tid  = threadIdx.x;
    const int wave = tid >> 6, lane = tid & 63;
    const int wm = wave >> 2, wn = wave & 3;     // 2M x 4N wave grid
    const int quad = lane >> 4, l16 = lane & 15;
    int bm, bn;
    xcd_swizzle(bm, bn);

    const int srow = lane >> 3;
    const int scol = ((lane & 7) * 8) ^ ((lane & 32) ? 16 : 0);
    size_t aoff[4], boff[NF];
    #pragma unroll
    for (int j = 0; j < 4; ++j) {
        int r = wave * 32 + j * 8 + srow;
        aoff[j] = (size_t)(bm * 256 + r) * K + scol;
    }
    #pragma unroll
    for (int j = 0; j < NF; ++j) {
        int r = wave * BROWS + j * 8 + srow;
        boff[j] = (size_t)(bn * BN + r) * K + scol;
    }
    const int lds0A = wave * 32 * 64;        // shorts; +j*512 per issue
    const int lds0B = wave * BROWS * 64;

    // ds_read swizzle: logical k-col quad*8 -> phys ^16 iff row&4 (= l16&4)
    const int ksw = (quad * 8) ^ ((l16 & 4) ? 16 : 0);

    v4f acc[8][NF];
    #pragma unroll
    for (int i = 0; i < 8; ++i)
        #pragma unroll
        for (int j = 0; j < NF; ++j)
            acc[i][j] = (v4f){0.f, 0.f, 0.f, 0.f};

    const int NT = K >> 6;
    #pragma unroll
    for (int j = 0; j < 4; ++j)
        gload16(A  + aoff[j], &sA[0][lds0A + j * 512]);
    #pragma unroll
    for (int j = 0; j < NF; ++j)
        gload16(BT + boff[j], &sB[0][lds0B + j * 512]);
    __syncthreads();

    for (int t = 0; t < NT; ++t) {
        const int buf = t & 1;
        if (t + 1 < NT) {
            const int ktn = (t + 1) << 6;
            #pragma unroll
            for (int j = 0; j < 4; ++j)
                gload16(A  + aoff[j] + ktn, &sA[buf ^ 1][lds0A + j * 512]);
            #pragma unroll
            for (int j = 0; j < NF; ++j)
                gload16(BT + boff[j] + ktn, &sB[buf ^ 1][lds0B + j * 512]);
        }

        v8bf bfr[NF][2];
        #pragma unroll
        for (int nt2 = 0; nt2 < NF; ++nt2)
            #pragma unroll
            for (int kc = 0; kc < 2; ++kc)
                bfr[nt2][kc] = *(const v8bf*)&sB[buf][
                    (wn * (NF * 16) + nt2 * 16 + l16) * 64 + kc * 32 + ksw];
        #pragma unroll
        for (int mq = 0; mq < 2; ++mq) {
            v8bf af[4][2];
            #pragma unroll
            for (int mt2 = 0; mt2 < 4; ++mt2)
                #pragma unroll
                for (int kc = 0; kc < 2; ++kc)
                    af[mt2][kc] = *(const v8bf*)&sA[buf][
                        (wm * 128 + mq * 64 + mt2 * 16 + l16) * 64 + kc * 32 + ksw];
            #pragma unroll
            for (int mt2 = 0; mt2 < 4; ++mt2)
                #pragma unroll
                for (int nt2 = 0; nt2 < NF; ++nt2)
                    #pragma unroll
                    for (int kc = 0; kc < 2; ++kc)
                        acc[mq * 4 + mt2][nt2] =
                            __builtin_amdgcn_mfma_f32_16x16x32_bf16(
                                af[mt2][kc], bfr[nt2][kc],
                                acc[mq * 4 + mt2][nt2], 0, 0, 0);
        }
        __syncthreads();   // drains vmcnt (tile t+1 landed) + lgkm (reads done)
    }

    #pragma unroll
    for (int mt = 0; mt < 8; ++mt) {
        int row = bm * 256 + wm * 128 + mt * 16 + quad * 4;
        #pragma unroll
        for (int nt = 0; nt < NF; ++nt) {
            int c0 = bn * BN + wn * (NF * 16) + nt * 16;
            int col = c0 + l16;
            float bv = bias ? bias[col] : 0.f;
            if (SPLIT_V && (c0 % 192) >= 128) {
                int hh = c0 / 192;
                int d  = (c0 % 192) - 128 + l16;
                int bb = row >> 11;
                int s  = row & 2047;
                v4us st;
                #pragma unroll
                for (int r = 0; r < 4; ++r)
                    st[r] = f2b(acc[mt][nt][r] + bv);
                *(v4us*)&VT[((size_t)(bb * 16 + hh) * 64 + d) * 2048 + s] = st;
            } else {
                float qs = (SPLIT_V && (c0 % 192) < 64) ? 0.18033688f : 1.0f;
                #pragma unroll
                for (int r = 0; r < 4; ++r) {
                    float v = (acc[mt][nt][r] + bv) * qs;
                    if (relu) v = fmaxf(v, 0.f);
                    C[(size_t)(row + r) * N + col] = f2b(v);
                }
            }
        }
    }
}

// ---------------------------------------------------------------------------
// MFMA flash attention v11 (r18): 512 threads / 8 waves, 16 q/wave, grid 512,
// single-barrier double-buffered K/V LDS. LDS 55296 B -> 2 blocks/CU.
// ---------------------------------------------------------------------------
__global__ __launch_bounds__(512) void attn_mfma(
    const unsigned short* __restrict__ qkv, const unsigned short* __restrict__ VT,
    unsigned short* __restrict__ av)
{
    __shared__ __align__(16) unsigned short sK[2][64 * 72];
    __shared__ __align__(16) unsigned short sVT[2][64 * 72];
    __shared__ __align__(16) unsigned short sP[8][16 * 72];
    const int tid  = threadIdx.x;
    const int wave = tid >> 6, lane = tid & 63;
    const int quad = lane >> 4, l16 = lane & 15;
    const int blk = blockIdx.x;
    const int xcd = blk & 7, local = blk >> 3;
    const int bh = xcd * 4 + (local & 3);     // all q-blocks of a bh on one XCD
    const int qb = local >> 2;                // [0,16): 128-row q-block
    const int h = bh & 15, b = bh >> 4;
    const int row0 = b * 2048;
    const int qbase = row0 + qb * 128 + wave * 16;
    const size_t qoff = (size_t)h * 192;
    const size_t koff = qoff + 64;

    v8bf qf[2];
    #pragma unroll
    for (int kc = 0; kc < 2; ++kc)
        qf[kc] = *(const v8bf*)&qkv[(size_t)(qbase + l16) * 3072
                                    + qoff + kc * 32 + quad * 8];

    v4f o[4];
    #pragma unroll
    for (int dt = 0; dt < 4; ++dt)
        o[dt] = (v4f){0.f, 0.f, 0.f, 0.f};
    float ll = 0.f;

    // staging: 512 threads cover 64x64 K tile and 64x64 V tile, 1 v8us each
    const int k_key = tid >> 3, k_oct = (tid & 7) * 8;
    const unsigned short* gK = qkv + (size_t)(row0 + k_key) * 3072 + koff + k_oct;
    const unsigned short* gV = VT + ((size_t)bh * 64 + k_key) * 2048 + k_oct;
    const size_t stepK = (size_t)64 * 3072;
    const size_t stepV = 64;

    v8us kreg = *(const v8us*)gK;
    v8us vreg = *(const v8us*)gV;
    gK += stepK; gV += stepV;

    for (int kt = 0; kt < 32; ++kt) {
        const int cur = kt & 1;
        *(v8us*)&sK[cur][k_key * 72 + k_oct]  = kreg;
        *(v8us*)&sVT[cur][k_key * 72 + k_oct] = vreg;
        __syncthreads();
        if (kt < 31) {
            kreg = *(const v8us*)gK;
            vreg = *(const v8us*)gV;
            gK += stepK; gV += stepV;
        }

        v4f sc[4];
        #pragma unroll
        for (int kk = 0; kk < 4; ++kk) {
            sc[kk] = (v4f){0.f, 0.f, 0.f, 0.f};
            #pragma unroll
            for (int kc = 0; kc < 2; ++kc) {
                v8bf ak = *(const v8bf*)&sK[cur][(kk * 16 + l16) * 72 + kc * 32 + quad * 8];
                sc[kk] = __builtin_amdgcn_mfma_f32_16x16x32_bf16(
                    ak, qf[kc], sc[kk], 0, 0, 0);
            }
        }

        float ps = 0.f;
        #pragma unroll
        for (int kk = 0; kk < 4; ++kk) {
            v4bf pk;
            #pragma unroll
            for (int rr = 0; rr < 4; ++rr) {
                float p = __builtin_amdgcn_exp2f(sc[kk][rr]);
                ps += p;
                pk[rr] = (__bf16)p;
            }
            *(v4bf*)&sP[wave][l16 * 72 + kk * 16 + quad * 4] = pk;
        }
        ll += ps;

        __asm__ volatile("s_waitcnt lgkmcnt(0)" ::: "memory");

        #pragma unroll
        for (int c = 0; c < 2; ++c) {
            union { v8bf v; v8us u; } u;
            u.u = *(const v8us*)&sP[wave][l16 * 72 + c * 32 + quad * 8];
            v8bf pb = u.v;
            #pragma unroll
            for (int dt = 0; dt < 4; ++dt) {
                v8bf va = *(const v8bf*)&sVT[cur][(dt * 16 + l16) * 72 + c * 32 + quad * 8];
                o[dt] = __builtin_amdgcn_mfma_f32_16x16x32_bf16(
                    va, pb, o[dt], 0, 0, 0);
            }
        }
    }

    float l = ll;
    l += __shfl_xor(l, 16, 64);
    l += __shfl_xor(l, 32, 64);
    float inv = 1.f / l;
    int qrow = qbase + l16;
    #pragma unroll
    for (int dt = 0; dt < 4; ++dt) {
        v4bf st;
        #pragma unroll
        for (int rr = 0; rr < 4; ++rr)
            st[rr] = (__bf16)(o[dt][rr] * inv);
        *(v4bf*)&av[(size_t)qrow * 1024 + h * 64 + dt * 16 + quad * 4] = st;
    }
}

// ---------------------------------------------------------------------------
// LN1 body (residual f32, out bf16, in-place safe).
// ---------------------------------------------------------------------------
__device__ __forceinline__ void ln_row_f32res(
    const unsigned short* __restrict__ a, const float* __restrict__ resid,
    const float* __restrict__ gamma, const float* __restrict__ beta,
    unsigned short* __restrict__ outp, int row, int tid)
{
    const size_t base = (size_t)row * 1024;
    const int c0 = tid * 4;
    ushort4 avv = *(const ushort4*)&a[base + c0];
    float4 rv = *(const float4*)&resid[base + c0];
    float y[4];
    y[0] = b2f(avv.x) + rv.x;
    y[1] = b2f(avv.y) + rv.y;
    y[2] = b2f(avv.z) + rv.z;
    y[3] = b2f(avv.w) + rv.w;
    float s  = y[0] + y[1] + y[2] + y[3];
    float ss = y[0]*y[0] + y[1]*y[1] + y[2]*y[2] + y[3]*y[3];
    #pragma unroll
    for (int off = 32; off; off >>= 1) {
        s  += __shfl_xor(s, off, 64);
        ss += __shfl_xor(ss, off, 64);
    }
    __shared__ float red[8];
    int wave = tid >> 6, lane = tid & 63;
    if (lane == 0) { red[wave] = s; red[4 + wave] = ss; }
    __syncthreads();
    s  = red[0] + red[1] + red[2] + red[3];
    ss = red[4] + red[5] + red[6] + red[7];
    float mean = s * (1.f / 1024.f);
    float var  = ss * (1.f / 1024.f) - mean * mean;
    float rstd = rsqrtf(var + 1e-5f);
    float4 gv = *(const float4*)&gamma[c0];
    float4 bv = *(const float4*)&beta[c0];
    ushort4 ov;
    ov.x = f2b(gv.x * (y[0] - mean) * rstd + bv.x);
    ov.y = f2b(gv.y * (y[1] - mean) * rstd + bv.y);
    ov.z = f2b(gv.z * (y[2] - mean) * rstd + bv.z);
    ov.w = f2b(gv.w * (y[3] - mean) * rstd + bv.w);
    *(ushort4*)&outp[base + c0] = ov;
}

// ---------------------------------------------------------------------------
// r23: LN1 (4096 rows) + W2T transpose (1024 tiles) fused into one launch.
// ---------------------------------------------------------------------------
__global__ __launch_bounds__(256) void ln1_w2t_fused(
    const unsigned short* __restrict__ a, const float* __restrict__ x,
    const float* __restrict__ gamma, const float* __restrict__ beta,
    unsigned short* __restrict__ h_out,
    const float* __restrict__ W2, unsigned short* __restrict__ W2T)
{
    const int b = blockIdx.x, tid = threadIdx.x;
    if (b < 4096) {
        ln_row_f32res(a, x, gamma, beta, h_out, b, tid);
    } else {
        int lb = b - 4096;                       // W2: [4096][1024] -> 64x16 tiles
        transpose_tile(W2, W2T, 4096, 1024, (lb / 16) * 64, (lb % 16) * 64, tid);
    }
}

// ---------------------------------------------------------------------------
// Fused residual-add + LayerNorm (standalone, used for LN2).
// ---------------------------------------------------------------------------
template<int RES_F32, int OUT_F32>
__global__ __launch_bounds__(256) void ln_fused(
    const unsigned short* __restrict__ a, const void* __restrict__ residv,
    const float* __restrict__ gamma, const float* __restrict__ beta,
    void* __restrict__ outv)
{
    const int row = blockIdx.x, tid = threadIdx.x;
    const size_t base = (size_t)row * 1024;
    const int c0 = tid * 4;
    ushort4 avv = *(const ushort4*)&a[base + c0];
    float y[4];
    if (RES_F32) {
        float4 rv = *(const float4*)((const float*)residv + base + c0);
        y[0] = b2f(avv.x) + rv.x;
        y[1] = b2f(avv.y) + rv.y;
        y[2] = b2f(avv.z) + rv.z;
        y[3] = b2f(avv.w) + rv.w;
    } else {
        ushort4 rv = *(const ushort4*)((const unsigned short*)residv + base + c0);
        y[0] = b2f(avv.x) + b2f(rv.x);
        y[1] = b2f(avv.y) + b2f(rv.y);
        y[2] = b2f(avv.z) + b2f(rv.z);
        y[3] = b2f(avv.w) + b2f(rv.w);
    }
    float s  = y[0] + y[1] + y[2] + y[3];
    float ss = y[0]*y[0] + y[1]*y[1] + y[2]*y[2] + y[3]*y[3];
    #pragma unroll
    for (int off = 32; off; off >>= 1) {
        s  += __shfl_xor(s, off, 64);
        ss += __shfl_xor(ss, off, 64);
    }
    __shared__ float red[8];
    int wave = tid >> 6, lane = tid & 63;
    if (lane == 0) { red[wave] = s; red[4 + wave] = ss; }
    __syncthreads();
    s  = red[0] + red[1] + red[2] + red[3];
    ss = red[4] + red[5] + red[6] + red[7];
    float mean = s * (1.f / 1024.f);
    float var  = ss * (1.f / 1024.f) - mean * mean;
    float rstd = rsqrtf(var + 1e-5f);
    float4 gv = *(const float4*)&gamma[c0];
    float4 bv = *(const float4*)&beta[c0];
    float r0 = gv.x * (y[0] - mean) * rstd + bv.x;
    float r1 = gv.y * (y[1] - mean) * rstd + bv.y;
    float r2 = gv.z * (y[2] - mean) * rstd + bv.z;
    float r3 = gv.w * (y[3] - mean) * rstd + bv.w;
    if (OUT_F32) {
        float4 ov = {r0, r1, r2, r3};
        *(float4*)((float*)outv + base + c0) = ov;
    } else {
        ushort4 ov;
        ov.x = f2b(r0); ov.y = f2b(r1); ov.z = f2b(r2); ov.w = f2b(r3);
        *(ushort4*)((unsigned short*)outv + base + c0) = ov;
    }
}

// ---------------------------------------------------------------------------
// r25 pipeline (8 launches), ws map as r21:
//  R0[0..12M): qkv Q/K -> ffn1(16M)
//  R0[12M..15M): WqkvT   R0[15M..16M): WoT
//  R1: VT -> attn_out -> h (LN1 in-place) -> residual for LN2
//  R2: xb -> av -> W2T
//  R3: W1T -> ffn2
// ---------------------------------------------------------------------------
extern "C" void kernel_launch(void* const* d_in, const int* in_sizes, int n_in,
                              void* d_out, int out_size, void* d_ws, size_t ws_size,
                              hipStream_t stream)
{
    (void)in_sizes; (void)n_in; (void)out_size; (void)ws_size;
    const float* x    = (const float*)d_in[0];
    const float* Wqkv = (const float*)d_in[1];
    const float* bqkv = (const float*)d_in[2];
    const float* Wo   = (const float*)d_in[3];
    const float* bo   = (const float*)d_in[4];
    const float* g1   = (const float*)d_in[5];
    const float* be1  = (const float*)d_in[6];
    const float* W1   = (const float*)d_in[7];
    const float* b1   = (const float*)d_in[8];
    const float* W2   = (const float*)d_in[9];
    const float* b2   = (const float*)d_in[10];
    const float* g2   = (const float*)d_in[11];
    const float* be2  = (const float*)d_in[12];
    float* out = (float*)d_out;

    unsigned short* R0 = (unsigned short*)d_ws;
    unsigned short* R1 = R0 + (size_t)16 * 1024 * 1024;
    unsigned short* R2 = R1 + (size_t)4 * 1024 * 1024;
    unsigned short* R3 = R2 + (size_t)4 * 1024 * 1024;
    unsigned short* WqkvT = R0 + (size_t)12 * 1024 * 1024;
    unsigned short* WoT   = R0 + (size_t)15 * 1024 * 1024;

    const int M = 4096;
    dim3 blk(256);

    // 1. prep: xb (R2), WqkvT, W1T (R3), WoT — one launch
    prep_fused<<<dim3(4096 + 768 + 1024 + 256), blk, 0, stream>>>(
        x, R2, Wqkv, WqkvT, W1, R3, Wo, WoT);
    // 2. qkv: Q(pre-scaled)/K -> R0, V transposed -> VT (R1)
    //    256x192 tile -> grid (16,16) = 256 blocks = full CU coverage
    gemm256<1, 3><<<dim3(16, 16), dim3(512), 0, stream>>>(R2, WqkvT, bqkv, R0, R1, M, 3072, 1024, 0);
    // 3. attention -> av (R2; xb dead)
    attn_mfma<<<dim3(512), dim3(512), 0, stream>>>(R0, R1, R2);
    // 4. attn_out = av @ Wo + bo -> R1 (VT dead)
    gemm_bt_n64<<<dim3(16, 32), blk, 0, stream>>>(R2, WoT, bo, R1, M, 1024, 1024, 0);
    // 5. h = LN1(attn_out + x) -> R1 in-place  +  W2T -> R2 (av dead) — fused
    ln1_w2t_fused<<<dim3(4096 + 1024), blk, 0, stream>>>(R1, x, g1, be1, R1, W2, R2);
    // 6. ffn1 = relu(h @ W1 + b1) -> R0 (qkv/WqkvT/WoT dead)
    gemm256<0, 4><<<dim3(16, 16), dim3(512), 0, stream>>>(R1, R3, b1, R0, nullptr, M, 4096, 1024, 1);
    // 7. ffn2 = ffn1 @ W2 + b2 -> R3 (W1T dead)
    gemm_bt_n64<<<dim3(16, 32), blk, 0, stream>>>(R0, R2, b2, R3, M, 1024, 4096, 0);
    // 8. out = LN2(ffn2 + h)
    ln_fused<0, 1><<<dim3(4096), blk, 0, stream>>>(R3, R1, g2, be2, out);
}

// Round 14
// 325.645 us; speedup vs baseline: 1.0890x; 1.0185x over previous
//
#include <hip/hip_runtime.h>
#include <stdint.h>

typedef float v4f __attribute__((ext_vector_type(4)));
typedef __bf16 v8bf __attribute__((ext_vector_type(8)));
typedef __bf16 v4bf __attribute__((ext_vector_type(4)));
typedef unsigned short v8us __attribute__((ext_vector_type(8)));
typedef unsigned short v4us __attribute__((ext_vector_type(4)));

__device__ __forceinline__ float b2f(unsigned short u) {
    union { float f; uint32_t i; } x; x.i = ((uint32_t)u) << 16; return x.f;
}
__device__ __forceinline__ unsigned short f2b(float f) {
    union { float f; uint32_t u; } x; x.f = f;
    uint32_t r = x.u + 0x7fffu + ((x.u >> 16) & 1u);
    return (unsigned short)(r >> 16);
}

// async global->LDS, 16B/lane. LDS dst must be wave-uniform; HW adds lane*16.
__device__ __forceinline__ void gload16(const unsigned short* g, unsigned short* l) {
    __builtin_amdgcn_global_load_lds(
        (const __attribute__((address_space(1))) void*)g,
        (__attribute__((address_space(3))) void*)l,
        16, 0, 0);
}

// ---------------------------------------------------------------------------
// Transpose tile body: W[K][N] fp32 -> WT[N][K] bf16, one 64x64 tile.
// ---------------------------------------------------------------------------
__device__ __forceinline__ void transpose_tile(
    const float* __restrict__ W, unsigned short* __restrict__ WT,
    int K, int N, int kb, int nb, int tid)
{
    __shared__ unsigned short t[64][65];
    const int r = tid >> 4, c4 = (tid & 15) * 4;
    #pragma unroll
    for (int i = 0; i < 4; ++i) {
        int k = r + i * 16;
        float4 v = *(const float4*)&W[(size_t)(kb + k) * N + nb + c4];
        t[c4 + 0][k] = f2b(v.x);
        t[c4 + 1][k] = f2b(v.y);
        t[c4 + 2][k] = f2b(v.z);
        t[c4 + 3][k] = f2b(v.w);
    }
    __syncthreads();
    #pragma unroll
    for (int i = 0; i < 4; ++i) {
        int n = r + i * 16;
        v4us o = {t[n][c4], t[n][c4 + 1], t[n][c4 + 2], t[n][c4 + 3]};
        *(v4us*)&WT[(size_t)(nb + n) * K + kb + c4] = o;
    }
}

// ---------------------------------------------------------------------------
// r21 prep_fused: x convert (4096 blocks) + WqkvT (768) + W1T (1024) +
// WoT (256) in ONE launch. Block-uniform branch.
// ---------------------------------------------------------------------------
__global__ __launch_bounds__(256) void prep_fused(
    const float* __restrict__ x, unsigned short* __restrict__ xb,
    const float* __restrict__ Wqkv, unsigned short* __restrict__ WqkvT,
    const float* __restrict__ W1, unsigned short* __restrict__ W1T,
    const float* __restrict__ Wo, unsigned short* __restrict__ WoT)
{
    const int b = blockIdx.x, tid = threadIdx.x;
    if (b < 4096) {
        int i = (b * 256 + tid) * 4;
        float4 v = *(const float4*)&x[i];
        v4us o = {f2b(v.x), f2b(v.y), f2b(v.z), f2b(v.w)};
        *(v4us*)&xb[i] = o;
    } else if (b < 4096 + 768) {
        int lb = b - 4096;                       // Wqkv: 48 x 16 tiles
        transpose_tile(Wqkv, WqkvT, 1024, 3072, (lb / 48) * 64, (lb % 48) * 64, tid);
    } else if (b < 4096 + 768 + 1024) {
        int lb = b - 4096 - 768;                 // W1: 64 x 16 tiles
        transpose_tile(W1, W1T, 1024, 4096, (lb / 64) * 64, (lb % 64) * 64, tid);
    } else {
        int lb = b - 4096 - 768 - 1024;          // Wo: 16 x 16 tiles
        transpose_tile(Wo, WoT, 1024, 1024, (lb / 16) * 64, (lb % 16) * 64, tid);
    }
}

// ---------------------------------------------------------------------------
// XCD-locality swizzle for GEMM grids (validated r14). MB must be %8.
// ---------------------------------------------------------------------------
__device__ __forceinline__ void xcd_swizzle(int& bm, int& bn) {
    int NB = gridDim.x, MB = gridDim.y;
    int flat = blockIdx.x + NB * blockIdx.y;
    int xcd = flat & 7, j = flat >> 3;
    int MBand = MB >> 3;
    bm = xcd * MBand + (j % MBand);
    bn = j / MBand;
}

// ---------------------------------------------------------------------------
// 128x64-tile GEMM for narrow-N (N=1024), BK=64. r20: depth-2 prefetch +
// single-barrier dbuf with STATIC register indexing (rule #20). K %128.
// ---------------------------------------------------------------------------
__global__ __launch_bounds__(256) void gemm_bt_n64(
    const unsigned short* __restrict__ A, const unsigned short* __restrict__ BT,
    const float* __restrict__ bias, unsigned short* __restrict__ C,
    int M, int N, int K, int relu)
{
    __shared__ __align__(16) unsigned short sA0[2][128 * 32];
    __shared__ __align__(16) unsigned short sB0[2][64 * 32];
    __shared__ __align__(16) unsigned short sA1[2][128 * 32];
    __shared__ __align__(16) unsigned short sB1[2][64 * 32];
    const int tid  = threadIdx.x;
    const int wave = tid >> 6, lane = tid & 63;
    const int wm = wave >> 1, wn = wave & 1;
    const int quad = lane >> 4, l16 = lane & 15;
    int bm, bn;
    xcd_swizzle(bm, bn);

    const int srow = lane >> 2, scol = (lane & 3) * 8;
    const unsigned short* ga0 = A  + (size_t)(bm * 128 + (wave * 2 + 0) * 16 + srow) * K + scol;
    const unsigned short* ga1 = A  + (size_t)(bm * 128 + (wave * 2 + 1) * 16 + srow) * K + scol;
    const unsigned short* gb0 = BT + (size_t)(bn * 64 + wave * 16 + srow) * K + scol;
    const int oa0 = (wave * 2 + 0) * 512 + lane * 8;
    const int oa1 = (wave * 2 + 1) * 512 + lane * 8;
    const int ob  = wave * 512 + lane * 8;

    v8us aR0[2][2], bR0[2], aR1[2][2], bR1[2];
    #pragma unroll
    for (int c = 0; c < 2; ++c) {
        aR0[c][0] = *(const v8us*)(ga0 + c * 32);
        aR0[c][1] = *(const v8us*)(ga1 + c * 32);
        bR0[c]    = *(const v8us*)(gb0 + c * 32);
        aR1[c][0] = *(const v8us*)(ga0 + 64 + c * 32);
        aR1[c][1] = *(const v8us*)(ga1 + 64 + c * 32);
        bR1[c]    = *(const v8us*)(gb0 + 64 + c * 32);
    }

    v4f acc[4][2];
    #pragma unroll
    for (int i = 0; i < 4; ++i)
        #pragma unroll
        for (int j = 0; j < 2; ++j)
            acc[i][j] = (v4f){0.f, 0.f, 0.f, 0.f};

    for (int kt = 0; kt < K; kt += 128) {
        // ---- half 0 ----
        #pragma unroll
        for (int c = 0; c < 2; ++c) {
            *(v8us*)&sA0[c][oa0] = aR0[c][0];
            *(v8us*)&sA0[c][oa1] = aR0[c][1];
            *(v8us*)&sB0[c][ob]  = bR0[c];
        }
        __syncthreads();
        if (kt + 128 < K) {
            const int kn = kt + 128;
            #pragma unroll
            for (int c = 0; c < 2; ++c) {
                aR0[c][0] = *(const v8us*)(ga0 + kn + c * 32);
                aR0[c][1] = *(const v8us*)(ga1 + kn + c * 32);
                bR0[c]    = *(const v8us*)(gb0 + kn + c * 32);
            }
        }
        #pragma unroll
        for (int c = 0; c < 2; ++c) {
            v8bf af[4], bfr[2];
            #pragma unroll
            for (int mt = 0; mt < 4; ++mt)
                af[mt] = *(const v8bf*)&sA0[c][(wm * 64 + mt * 16 + l16) * 32 + quad * 8];
            #pragma unroll
            for (int nt = 0; nt < 2; ++nt)
                bfr[nt] = *(const v8bf*)&sB0[c][(wn * 32 + nt * 16 + l16) * 32 + quad * 8];
            #pragma unroll
            for (int mt = 0; mt < 4; ++mt)
                #pragma unroll
                for (int nt = 0; nt < 2; ++nt)
                    acc[mt][nt] = __builtin_amdgcn_mfma_f32_16x16x32_bf16(
                        af[mt], bfr[nt], acc[mt][nt], 0, 0, 0);
        }

        // ---- half 1 ----
        #pragma unroll
        for (int c = 0; c < 2; ++c) {
            *(v8us*)&sA1[c][oa0] = aR1[c][0];
            *(v8us*)&sA1[c][oa1] = aR1[c][1];
            *(v8us*)&sB1[c][ob]  = bR1[c];
        }
        __syncthreads();
        if (kt + 192 < K) {
            const int kn = kt + 192;
            #pragma unroll
            for (int c = 0; c < 2; ++c) {
                aR1[c][0] = *(const v8us*)(ga0 + kn + c * 32);
                aR1[c][1] = *(const v8us*)(ga1 + kn + c * 32);
                bR1[c]    = *(const v8us*)(gb0 + kn + c * 32);
            }
        }
        #pragma unroll
        for (int c = 0; c < 2; ++c) {
            v8bf af[4], bfr[2];
            #pragma unroll
            for (int mt = 0; mt < 4; ++mt)
                af[mt] = *(const v8bf*)&sA1[c][(wm * 64 + mt * 16 + l16) * 32 + quad * 8];
            #pragma unroll
            for (int nt = 0; nt < 2; ++nt)
                bfr[nt] = *(const v8bf*)&sB1[c][(wn * 32 + nt * 16 + l16) * 32 + quad * 8];
            #pragma unroll
            for (int mt = 0; mt < 4; ++mt)
                #pragma unroll
                for (int nt = 0; nt < 2; ++nt)
                    acc[mt][nt] = __builtin_amdgcn_mfma_f32_16x16x32_bf16(
                        af[mt], bfr[nt], acc[mt][nt], 0, 0, 0);
        }
    }

    #pragma unroll
    for (int mt = 0; mt < 4; ++mt) {
        #pragma unroll
        for (int nt = 0; nt < 2; ++nt) {
            int col = bn * 64 + wn * 32 + nt * 16 + l16;
            float bv = bias ? bias[col] : 0.f;
            #pragma unroll
            for (int r = 0; r < 4; ++r) {
                int row = bm * 128 + wm * 64 + mt * 16 + quad * 4 + r;
                float v = acc[mt][nt][r] + bv;
                if (relu) v = fmaxf(v, 0.f);
                C[(size_t)row * N + col] = f2b(v);
            }
        }
    }
}

// ---------------------------------------------------------------------------
// gemm256 (r21 structure), r25: templated on NF = N-fragments per wave.
// Tile = 256 x (NF*64). NF=4 -> 256x256 (FFN1). NF=3 -> 256x192 (QKV, full
// CU coverage; verified r25, -6.3us). LDS: A 64KB + B NF*16KB.
// 2-phase global_load_lds + st_16x32 swizzle; 8 waves (2M x 4N).
// ---------------------------------------------------------------------------
template<int SPLIT_V, int NF>
__global__ __launch_bounds__(512) void gemm256(
    const unsigned short* __restrict__ A, const unsigned short* __restrict__ BT,
    const float* __restrict__ bias, unsigned short* __restrict__ C,
    unsigned short* __restrict__ VT, int M, int N, int K, int relu)
{
    constexpr int BN = NF * 64;              // 256 or 192
    constexpr int BROWS = BN / 8;            // B rows staged per wave
    __shared__ __align__(16) unsigned short sA[2][256 * 64];
    __shared__ __align__(16) unsigned short sB[2][BN * 64];
    const int tid  = threadIdx.x;
    const int wave = tid >> 6, lane = tid & 63;
    const int wm = wave >> 2, wn = wave & 3;     // 2M x 4N wave grid
    const int quad = lane >> 4, l16 = lane & 15;
    int bm, bn;
    xcd_swizzle(bm, bn);

    const int srow = lane >> 3;
    const int scol = ((lane & 7) * 8) ^ ((lane & 32) ? 16 : 0);
    size_t aoff[4], boff[NF];
    #pragma unroll
    for (int j = 0; j < 4; ++j) {
        int r = wave * 32 + j * 8 + srow;
        aoff[j] = (size_t)(bm * 256 + r) * K + scol;
    }
    #pragma unroll
    for (int j = 0; j < NF; ++j) {
        int r = wave * BROWS + j * 8 + srow;
        boff[j] = (size_t)(bn * BN + r) * K + scol;
    }
    const int lds0A = wave * 32 * 64;        // shorts; +j*512 per issue
    const int lds0B = wave * BROWS * 64;

    // ds_read swizzle: logical k-col quad*8 -> phys ^16 iff row&4 (= l16&4)
    const int ksw = (quad * 8) ^ ((l16 & 4) ? 16 : 0);

    v4f acc[8][NF];
    #pragma unroll
    for (int i = 0; i < 8; ++i)
        #pragma unroll
        for (int j = 0; j < NF; ++j)
            acc[i][j] = (v4f){0.f, 0.f, 0.f, 0.f};

    const int NT = K >> 6;
    #pragma unroll
    for (int j = 0; j < 4; ++j)
        gload16(A  + aoff[j], &sA[0][lds0A + j * 512]);
    #pragma unroll
    for (int j = 0; j < NF; ++j)
        gload16(BT + boff[j], &sB[0][lds0B + j * 512]);
    __syncthreads();

    for (int t = 0; t < NT; ++t) {
        const int buf = t & 1;
        if (t + 1 < NT) {
            const int ktn = (t + 1) << 6;
            #pragma unroll
            for (int j = 0; j < 4; ++j)
                gload16(A  + aoff[j] + ktn, &sA[buf ^ 1][lds0A + j * 512]);
            #pragma unroll
            for (int j = 0; j < NF; ++j)
                gload16(BT + boff[j] + ktn, &sB[buf ^ 1][lds0B + j * 512]);
        }

        v8bf bfr[NF][2];
        #pragma unroll
        for (int nt2 = 0; nt2 < NF; ++nt2)
            #pragma unroll
            for (int kc = 0; kc < 2; ++kc)
                bfr[nt2][kc] = *(const v8bf*)&sB[buf][
                    (wn * (NF * 16) + nt2 * 16 + l16) * 64 + kc * 32 + ksw];
        #pragma unroll
        for (int mq = 0; mq < 2; ++mq) {
            v8bf af[4][2];
            #pragma unroll
            for (int mt2 = 0; mt2 < 4; ++mt2)
                #pragma unroll
                for (int kc = 0; kc < 2; ++kc)
                    af[mt2][kc] = *(const v8bf*)&sA[buf][
                        (wm * 128 + mq * 64 + mt2 * 16 + l16) * 64 + kc * 32 + ksw];
            #pragma unroll
            for (int mt2 = 0; mt2 < 4; ++mt2)
                #pragma unroll
                for (int nt2 = 0; nt2 < NF; ++nt2)
                    #pragma unroll
                    for (int kc = 0; kc < 2; ++kc)
                        acc[mq * 4 + mt2][nt2] =
                            __builtin_amdgcn_mfma_f32_16x16x32_bf16(
                                af[mt2][kc], bfr[nt2][kc],
                                acc[mq * 4 + mt2][nt2], 0, 0, 0);
        }
        __syncthreads();   // drains vmcnt (tile t+1 landed) + lgkm (reads done)
    }

    #pragma unroll
    for (int mt = 0; mt < 8; ++mt) {
        int row = bm * 256 + wm * 128 + mt * 16 + quad * 4;
        #pragma unroll
        for (int nt = 0; nt < NF; ++nt) {
            int c0 = bn * BN + wn * (NF * 16) + nt * 16;
            int col = c0 + l16;
            float bv = bias ? bias[col] : 0.f;
            if (SPLIT_V && (c0 % 192) >= 128) {
                int hh = c0 / 192;
                int d  = (c0 % 192) - 128 + l16;
                int bb = row >> 11;
                int s  = row & 2047;
                v4us st;
                #pragma unroll
                for (int r = 0; r < 4; ++r)
                    st[r] = f2b(acc[mt][nt][r] + bv);
                *(v4us*)&VT[((size_t)(bb * 16 + hh) * 64 + d) * 2048 + s] = st;
            } else {
                float qs = (SPLIT_V && (c0 % 192) < 64) ? 0.18033688f : 1.0f;
                #pragma unroll
                for (int r = 0; r < 4; ++r) {
                    float v = (acc[mt][nt][r] + bv) * qs;
                    if (relu) v = fmaxf(v, 0.f);
                    C[(size_t)(row + r) * N + col] = f2b(v);
                }
            }
        }
    }
}

// ---------------------------------------------------------------------------
// MFMA flash attention v12 (r26): 256 q-rows/block (32 q/wave x 8 waves),
// grid 256 = 1 block/CU. Inverse of r1's failed q-split: K/V staging per
// unit compute HALVES (one 2048-key stream now feeds 256 rows, was 128).
// Wave-level code verbatim from the verified r14 32-q/wave kernel; r18
// single-barrier double-buffered K/V LDS kept. LDS 73728 B.
// ---------------------------------------------------------------------------
__global__ __launch_bounds__(512) void attn_mfma(
    const unsigned short* __restrict__ qkv, const unsigned short* __restrict__ VT,
    unsigned short* __restrict__ av)
{
    __shared__ __align__(16) unsigned short sK[2][64 * 72];
    __shared__ __align__(16) unsigned short sVT[2][64 * 72];
    __shared__ __align__(16) unsigned short sP[8][32 * 72];
    const int tid  = threadIdx.x;
    const int wave = tid >> 6, lane = tid & 63;
    const int quad = lane >> 4, l16 = lane & 15;
    const int blk = blockIdx.x;
    const int xcd = blk & 7, local = blk >> 3;   // 256 blocks: local in [0,32)
    const int bh = xcd * 4 + (local & 3);        // all q-blocks of a bh on one XCD
    const int qb = local >> 2;                   // [0,8): 256-row q-block
    const int h = bh & 15, b = bh >> 4;
    const int row0 = b * 2048;
    const int qbase = row0 + qb * 256 + wave * 32;
    const size_t qoff = (size_t)h * 192;
    const size_t koff = qoff + 64;

    v8bf qf[2][2];
    #pragma unroll
    for (int qt = 0; qt < 2; ++qt)
        #pragma unroll
        for (int kc = 0; kc < 2; ++kc)
            qf[qt][kc] = *(const v8bf*)&qkv[(size_t)(qbase + qt * 16 + l16) * 3072
                                            + qoff + kc * 32 + quad * 8];

    v4f o[4][2];
    #pragma unroll
    for (int dt = 0; dt < 4; ++dt)
        #pragma unroll
        for (int qt = 0; qt < 2; ++qt)
            o[dt][qt] = (v4f){0.f, 0.f, 0.f, 0.f};
    float ll[2] = {0.f, 0.f};

    // staging: 512 threads cover 64x64 K tile and 64x64 V tile, 1 v8us each
    const int k_key = tid >> 3, k_oct = (tid & 7) * 8;
    const unsigned short* gK = qkv + (size_t)(row0 + k_key) * 3072 + koff + k_oct;
    const unsigned short* gV = VT + ((size_t)bh * 64 + k_key) * 2048 + k_oct;
    const size_t stepK = (size_t)64 * 3072;
    const size_t stepV = 64;

    v8us kreg = *(const v8us*)gK;
    v8us vreg = *(const v8us*)gV;
    gK += stepK; gV += stepV;

    for (int kt = 0; kt < 32; ++kt) {
        const int cur = kt & 1;
        *(v8us*)&sK[cur][k_key * 72 + k_oct]  = kreg;
        *(v8us*)&sVT[cur][k_key * 72 + k_oct] = vreg;
        __syncthreads();
        if (kt < 31) {
            kreg = *(const v8us*)gK;
            vreg = *(const v8us*)gV;
            gK += stepK; gV += stepV;
        }

        v4f sc[4][2];
        #pragma unroll
        for (int kk = 0; kk < 4; ++kk) {
            #pragma unroll
            for (int qt = 0; qt < 2; ++qt)
                sc[kk][qt] = (v4f){0.f, 0.f, 0.f, 0.f};
            #pragma unroll
            for (int kc = 0; kc < 2; ++kc) {
                v8bf ak = *(const v8bf*)&sK[cur][(kk * 16 + l16) * 72 + kc * 32 + quad * 8];
                #pragma unroll
                for (int qt = 0; qt < 2; ++qt)
                    sc[kk][qt] = __builtin_amdgcn_mfma_f32_16x16x32_bf16(
                        ak, qf[qt][kc], sc[kk][qt], 0, 0, 0);
            }
        }

        #pragma unroll
        for (int qt = 0; qt < 2; ++qt) {
            float ps = 0.f;
            #pragma unroll
            for (int kk = 0; kk < 4; ++kk) {
                v4bf pk;
                #pragma unroll
                for (int rr = 0; rr < 4; ++rr) {
                    float p = __builtin_amdgcn_exp2f(sc[kk][qt][rr]);
                    ps += p;
                    pk[rr] = (__bf16)p;
                }
                *(v4bf*)&sP[wave][(qt * 16 + l16) * 72 + kk * 16 + quad * 4] = pk;
            }
            ll[qt] += ps;
        }

        __asm__ volatile("s_waitcnt lgkmcnt(0)" ::: "memory");

        #pragma unroll
        for (int c = 0; c < 2; ++c) {
            v8bf pb[2];
            #pragma unroll
            for (int qt = 0; qt < 2; ++qt) {
                union { v8bf v; v8us u; } u;
                u.u = *(const v8us*)&sP[wave][(qt * 16 + l16) * 72 + c * 32 + quad * 8];
                pb[qt] = u.v;
            }
            #pragma unroll
            for (int dt = 0; dt < 4; ++dt) {
                v8bf va = *(const v8bf*)&sVT[cur][(dt * 16 + l16) * 72 + c * 32 + quad * 8];
                #pragma unroll
                for (int qt = 0; qt < 2; ++qt)
                    o[dt][qt] = __builtin_amdgcn_mfma_f32_16x16x32_bf16(
                        va, pb[qt], o[dt][qt], 0, 0, 0);
            }
        }
    }

    #pragma unroll
    for (int qt = 0; qt < 2; ++qt) {
        float l = ll[qt];
        l += __shfl_xor(l, 16, 64);
        l += __shfl_xor(l, 32, 64);
        float inv = 1.f / l;
        int qrow = qbase + qt * 16 + l16;
        #pragma unroll
        for (int dt = 0; dt < 4; ++dt) {
            v4bf st;
            #pragma unroll
            for (int rr = 0; rr < 4; ++rr)
                st[rr] = (__bf16)(o[dt][qt][rr] * inv);
            *(v4bf*)&av[(size_t)qrow * 1024 + h * 64 + dt * 16 + quad * 4] = st;
        }
    }
}

// ---------------------------------------------------------------------------
// LN1 body (residual f32, out bf16, in-place safe).
// ---------------------------------------------------------------------------
__device__ __forceinline__ void ln_row_f32res(
    const unsigned short* __restrict__ a, const float* __restrict__ resid,
    const float* __restrict__ gamma, const float* __restrict__ beta,
    unsigned short* __restrict__ outp, int row, int tid)
{
    const size_t base = (size_t)row * 1024;
    const int c0 = tid * 4;
    ushort4 avv = *(const ushort4*)&a[base + c0];
    float4 rv = *(const float4*)&resid[base + c0];
    float y[4];
    y[0] = b2f(avv.x) + rv.x;
    y[1] = b2f(avv.y) + rv.y;
    y[2] = b2f(avv.z) + rv.z;
    y[3] = b2f(avv.w) + rv.w;
    float s  = y[0] + y[1] + y[2] + y[3];
    float ss = y[0]*y[0] + y[1]*y[1] + y[2]*y[2] + y[3]*y[3];
    #pragma unroll
    for (int off = 32; off; off >>= 1) {
        s  += __shfl_xor(s, off, 64);
        ss += __shfl_xor(ss, off, 64);
    }
    __shared__ float red[8];
    int wave = tid >> 6, lane = tid & 63;
    if (lane == 0) { red[wave] = s; red[4 + wave] = ss; }
    __syncthreads();
    s  = red[0] + red[1] + red[2] + red[3];
    ss = red[4] + red[5] + red[6] + red[7];
    float mean = s * (1.f / 1024.f);
    float var  = ss * (1.f / 1024.f) - mean * mean;
    float rstd = rsqrtf(var + 1e-5f);
    float4 gv = *(const float4*)&gamma[c0];
    float4 bv = *(const float4*)&beta[c0];
    ushort4 ov;
    ov.x = f2b(gv.x * (y[0] - mean) * rstd + bv.x);
    ov.y = f2b(gv.y * (y[1] - mean) * rstd + bv.y);
    ov.z = f2b(gv.z * (y[2] - mean) * rstd + bv.z);
    ov.w = f2b(gv.w * (y[3] - mean) * rstd + bv.w);
    *(ushort4*)&outp[base + c0] = ov;
}

// ---------------------------------------------------------------------------
// r23: LN1 (4096 rows) + W2T transpose (1024 tiles) fused into one launch.
// ---------------------------------------------------------------------------
__global__ __launch_bounds__(256) void ln1_w2t_fused(
    const unsigned short* __restrict__ a, const float* __restrict__ x,
    const float* __restrict__ gamma, const float* __restrict__ beta,
    unsigned short* __restrict__ h_out,
    const float* __restrict__ W2, unsigned short* __restrict__ W2T)
{
    const int b = blockIdx.x, tid = threadIdx.x;
    if (b < 4096) {
        ln_row_f32res(a, x, gamma, beta, h_out, b, tid);
    } else {
        int lb = b - 4096;                       // W2: [4096][1024] -> 64x16 tiles
        transpose_tile(W2, W2T, 4096, 1024, (lb / 16) * 64, (lb % 16) * 64, tid);
    }
}

// ---------------------------------------------------------------------------
// Fused residual-add + LayerNorm (standalone, used for LN2).
// ---------------------------------------------------------------------------
template<int RES_F32, int OUT_F32>
__global__ __launch_bounds__(256) void ln_fused(
    const unsigned short* __restrict__ a, const void* __restrict__ residv,
    const float* __restrict__ gamma, const float* __restrict__ beta,
    void* __restrict__ outv)
{
    const int row = blockIdx.x, tid = threadIdx.x;
    const size_t base = (size_t)row * 1024;
    const int c0 = tid * 4;
    ushort4 avv = *(const ushort4*)&a[base + c0];
    float y[4];
    if (RES_F32) {
        float4 rv = *(const float4*)((const float*)residv + base + c0);
        y[0] = b2f(avv.x) + rv.x;
        y[1] = b2f(avv.y) + rv.y;
        y[2] = b2f(avv.z) + rv.z;
        y[3] = b2f(avv.w) + rv.w;
    } else {
        ushort4 rv = *(const ushort4*)((const unsigned short*)residv + base + c0);
        y[0] = b2f(avv.x) + b2f(rv.x);
        y[1] = b2f(avv.y) + b2f(rv.y);
        y[2] = b2f(avv.z) + b2f(rv.z);
        y[3] = b2f(avv.w) + b2f(rv.w);
    }
    float s  = y[0] + y[1] + y[2] + y[3];
    float ss = y[0]*y[0] + y[1]*y[1] + y[2]*y[2] + y[3]*y[3];
    #pragma unroll
    for (int off = 32; off; off >>= 1) {
        s  += __shfl_xor(s, off, 64);
        ss += __shfl_xor(ss, off, 64);
    }
    __shared__ float red[8];
    int wave = tid >> 6, lane = tid & 63;
    if (lane == 0) { red[wave] = s; red[4 + wave] = ss; }
    __syncthreads();
    s  = red[0] + red[1] + red[2] + red[3];
    ss = red[4] + red[5] + red[6] + red[7];
    float mean = s * (1.f / 1024.f);
    float var  = ss * (1.f / 1024.f) - mean * mean;
    float rstd = rsqrtf(var + 1e-5f);
    float4 gv = *(const float4*)&gamma[c0];
    float4 bv = *(const float4*)&beta[c0];
    float r0 = gv.x * (y[0] - mean) * rstd + bv.x;
    float r1 = gv.y * (y[1] - mean) * rstd + bv.y;
    float r2 = gv.z * (y[2] - mean) * rstd + bv.z;
    float r3 = gv.w * (y[3] - mean) * rstd + bv.w;
    if (OUT_F32) {
        float4 ov = {r0, r1, r2, r3};
        *(float4*)((float*)outv + base + c0) = ov;
    } else {
        ushort4 ov;
        ov.x = f2b(r0); ov.y = f2b(r1); ov.z = f2b(r2); ov.w = f2b(r3);
        *(ushort4*)((unsigned short*)outv + base + c0) = ov;
    }
}

// ---------------------------------------------------------------------------
// r26 pipeline (8 launches), ws map as r21:
//  R0[0..12M): qkv Q/K -> ffn1(16M)
//  R0[12M..15M): WqkvT   R0[15M..16M): WoT
//  R1: VT -> attn_out -> h (LN1 in-place) -> residual for LN2
//  R2: xb -> av -> W2T
//  R3: W1T -> ffn2
// ---------------------------------------------------------------------------
extern "C" void kernel_launch(void* const* d_in, const int* in_sizes, int n_in,
                              void* d_out, int out_size, void* d_ws, size_t ws_size,
                              hipStream_t stream)
{
    (void)in_sizes; (void)n_in; (void)out_size; (void)ws_size;
    const float* x    = (const float*)d_in[0];
    const float* Wqkv = (const float*)d_in[1];
    const float* bqkv = (const float*)d_in[2];
    const float* Wo   = (const float*)d_in[3];
    const float* bo   = (const float*)d_in[4];
    const float* g1   = (const float*)d_in[5];
    const float* be1  = (const float*)d_in[6];
    const float* W1   = (const float*)d_in[7];
    const float* b1   = (const float*)d_in[8];
    const float* W2   = (const float*)d_in[9];
    const float* b2   = (const float*)d_in[10];
    const float* g2   = (const float*)d_in[11];
    const float* be2  = (const float*)d_in[12];
    float* out = (float*)d_out;

    unsigned short* R0 = (unsigned short*)d_ws;
    unsigned short* R1 = R0 + (size_t)16 * 1024 * 1024;
    unsigned short* R2 = R1 + (size_t)4 * 1024 * 1024;
    unsigned short* R3 = R2 + (size_t)4 * 1024 * 1024;
    unsigned short* WqkvT = R0 + (size_t)12 * 1024 * 1024;
    unsigned short* WoT   = R0 + (size_t)15 * 1024 * 1024;

    const int M = 4096;
    dim3 blk(256);

    // 1. prep: xb (R2), WqkvT, W1T (R3), WoT — one launch
    prep_fused<<<dim3(4096 + 768 + 1024 + 256), blk, 0, stream>>>(
        x, R2, Wqkv, WqkvT, W1, R3, Wo, WoT);
    // 2. qkv: Q(pre-scaled)/K -> R0, V transposed -> VT (R1); 256x192 tile
    gemm256<1, 3><<<dim3(16, 16), dim3(512), 0, stream>>>(R2, WqkvT, bqkv, R0, R1, M, 3072, 1024, 0);
    // 3. attention -> av (R2; xb dead): 256 q-rows/block, grid 256
    attn_mfma<<<dim3(256), dim3(512), 0, stream>>>(R0, R1, R2);
    // 4. attn_out = av @ Wo + bo -> R1 (VT dead)
    gemm_bt_n64<<<dim3(16, 32), blk, 0, stream>>>(R2, WoT, bo, R1, M, 1024, 1024, 0);
    // 5. h = LN1(attn_out + x) -> R1 in-place  +  W2T -> R2 (av dead) — fused
    ln1_w2t_fused<<<dim3(4096 + 1024), blk, 0, stream>>>(R1, x, g1, be1, R1, W2, R2);
    // 6. ffn1 = relu(h @ W1 + b1) -> R0 (qkv/WqkvT/WoT dead)
    gemm256<0, 4><<<dim3(16, 16), dim3(512), 0, stream>>>(R1, R3, b1, R0, nullptr, M, 4096, 1024, 1);
    // 7. ffn2 = ffn1 @ W2 + b2 -> R3 (W1T dead)
    gemm_bt_n64<<<dim3(16, 32), blk, 0, stream>>>(R0, R2, b2, R3, M, 1024, 4096, 0);
    // 8. out = LN2(ffn2 + h)
    ln_fused<0, 1><<<dim3(4096), blk, 0, stream>>>(R3, R1, g2, be2, out);
}

// Round 17
// 324.071 us; speedup vs baseline: 1.0943x; 1.0049x over previous
//
#include <hip/hip_runtime.h>
#include <stdint.h>

typedef float v4f __attribute__((ext_vector_type(4)));
typedef __bf16 v8bf __attribute__((ext_vector_type(8)));
typedef __bf16 v4bf __attribute__((ext_vector_type(4)));
typedef unsigned short v8us __attribute__((ext_vector_type(8)));
typedef unsigned short v4us __attribute__((ext_vector_type(4)));

__device__ __forceinline__ float b2f(unsigned short u) {
    union { float f; uint32_t i; } x; x.i = ((uint32_t)u) << 16; return x.f;
}
__device__ __forceinline__ unsigned short f2b(float f) {
    union { float f; uint32_t u; } x; x.f = f;
    uint32_t r = x.u + 0x7fffu + ((x.u >> 16) & 1u);
    return (unsigned short)(r >> 16);
}

// async global->LDS, 16B/lane. LDS dst must be wave-uniform; HW adds lane*16.
__device__ __forceinline__ void gload16(const unsigned short* g, unsigned short* l) {
    __builtin_amdgcn_global_load_lds(
        (const __attribute__((address_space(1))) void*)g,
        (__attribute__((address_space(3))) void*)l,
        16, 0, 0);
}

// ---------------------------------------------------------------------------
// Transpose tile body: W[K][N] fp32 -> WT[N][K] bf16, one 64x64 tile.
// ---------------------------------------------------------------------------
__device__ __forceinline__ void transpose_tile(
    const float* __restrict__ W, unsigned short* __restrict__ WT,
    int K, int N, int kb, int nb, int tid)
{
    __shared__ unsigned short t[64][65];
    const int r = tid >> 4, c4 = (tid & 15) * 4;
    #pragma unroll
    for (int i = 0; i < 4; ++i) {
        int k = r + i * 16;
        float4 v = *(const float4*)&W[(size_t)(kb + k) * N + nb + c4];
        t[c4 + 0][k] = f2b(v.x);
        t[c4 + 1][k] = f2b(v.y);
        t[c4 + 2][k] = f2b(v.z);
        t[c4 + 3][k] = f2b(v.w);
    }
    __syncthreads();
    #pragma unroll
    for (int i = 0; i < 4; ++i) {
        int n = r + i * 16;
        v4us o = {t[n][c4], t[n][c4 + 1], t[n][c4 + 2], t[n][c4 + 3]};
        *(v4us*)&WT[(size_t)(nb + n) * K + kb + c4] = o;
    }
}

// ---------------------------------------------------------------------------
// r21 prep_fused: x convert (4096 blocks) + WqkvT (768) + W1T (1024) +
// WoT (256) in ONE launch. Block-uniform branch.
// ---------------------------------------------------------------------------
__global__ __launch_bounds__(256) void prep_fused(
    const float* __restrict__ x, unsigned short* __restrict__ xb,
    const float* __restrict__ Wqkv, unsigned short* __restrict__ WqkvT,
    const float* __restrict__ W1, unsigned short* __restrict__ W1T,
    const float* __restrict__ Wo, unsigned short* __restrict__ WoT)
{
    const int b = blockIdx.x, tid = threadIdx.x;
    if (b < 4096) {
        int i = (b * 256 + tid) * 4;
        float4 v = *(const float4*)&x[i];
        v4us o = {f2b(v.x), f2b(v.y), f2b(v.z), f2b(v.w)};
        *(v4us*)&xb[i] = o;
    } else if (b < 4096 + 768) {
        int lb = b - 4096;                       // Wqkv: 48 x 16 tiles
        transpose_tile(Wqkv, WqkvT, 1024, 3072, (lb / 48) * 64, (lb % 48) * 64, tid);
    } else if (b < 4096 + 768 + 1024) {
        int lb = b - 4096 - 768;                 // W1: 64 x 16 tiles
        transpose_tile(W1, W1T, 1024, 4096, (lb / 64) * 64, (lb % 64) * 64, tid);
    } else {
        int lb = b - 4096 - 768 - 1024;          // Wo: 16 x 16 tiles
        transpose_tile(Wo, WoT, 1024, 1024, (lb / 16) * 64, (lb % 16) * 64, tid);
    }
}

// ---------------------------------------------------------------------------
// XCD-locality swizzle for GEMM grids (validated r14). MB must be %8.
// ---------------------------------------------------------------------------
__device__ __forceinline__ void xcd_swizzle(int& bm, int& bn) {
    int NB = gridDim.x, MB = gridDim.y;
    int flat = blockIdx.x + NB * blockIdx.y;
    int xcd = flat & 7, j = flat >> 3;
    int MBand = MB >> 3;
    bm = xcd * MBand + (j % MBand);
    bn = j / MBand;
}

// ---------------------------------------------------------------------------
// 128x64-tile GEMM for narrow-N (N=1024), BK=64. r20 (verified 6 rounds):
// depth-2 prefetch + single-barrier dbuf with STATIC register indexing
// (rule #20). K %128. Used for Wo and FFN2.
// (r27 gload_lds port failed the bench twice -> reverted per pre-commit.)
// ---------------------------------------------------------------------------
__global__ __launch_bounds__(256) void gemm_bt_n64(
    const unsigned short* __restrict__ A, const unsigned short* __restrict__ BT,
    const float* __restrict__ bias, unsigned short* __restrict__ C,
    int M, int N, int K, int relu)
{
    __shared__ __align__(16) unsigned short sA0[2][128 * 32];
    __shared__ __align__(16) unsigned short sB0[2][64 * 32];
    __shared__ __align__(16) unsigned short sA1[2][128 * 32];
    __shared__ __align__(16) unsigned short sB1[2][64 * 32];
    const int tid  = threadIdx.x;
    const int wave = tid >> 6, lane = tid & 63;
    const int wm = wave >> 1, wn = wave & 1;
    const int quad = lane >> 4, l16 = lane & 15;
    int bm, bn;
    xcd_swizzle(bm, bn);

    const int srow = lane >> 2, scol = (lane & 3) * 8;
    const unsigned short* ga0 = A  + (size_t)(bm * 128 + (wave * 2 + 0) * 16 + srow) * K + scol;
    const unsigned short* ga1 = A  + (size_t)(bm * 128 + (wave * 2 + 1) * 16 + srow) * K + scol;
    const unsigned short* gb0 = BT + (size_t)(bn * 64 + wave * 16 + srow) * K + scol;
    const int oa0 = (wave * 2 + 0) * 512 + lane * 8;
    const int oa1 = (wave * 2 + 1) * 512 + lane * 8;
    const int ob  = wave * 512 + lane * 8;

    v8us aR0[2][2], bR0[2], aR1[2][2], bR1[2];
    #pragma unroll
    for (int c = 0; c < 2; ++c) {
        aR0[c][0] = *(const v8us*)(ga0 + c * 32);
        aR0[c][1] = *(const v8us*)(ga1 + c * 32);
        bR0[c]    = *(const v8us*)(gb0 + c * 32);
        aR1[c][0] = *(const v8us*)(ga0 + 64 + c * 32);
        aR1[c][1] = *(const v8us*)(ga1 + 64 + c * 32);
        bR1[c]    = *(const v8us*)(gb0 + 64 + c * 32);
    }

    v4f acc[4][2];
    #pragma unroll
    for (int i = 0; i < 4; ++i)
        #pragma unroll
        for (int j = 0; j < 2; ++j)
            acc[i][j] = (v4f){0.f, 0.f, 0.f, 0.f};

    for (int kt = 0; kt < K; kt += 128) {
        // ---- half 0 ----
        #pragma unroll
        for (int c = 0; c < 2; ++c) {
            *(v8us*)&sA0[c][oa0] = aR0[c][0];
            *(v8us*)&sA0[c][oa1] = aR0[c][1];
            *(v8us*)&sB0[c][ob]  = bR0[c];
        }
        __syncthreads();
        if (kt + 128 < K) {
            const int kn = kt + 128;
            #pragma unroll
            for (int c = 0; c < 2; ++c) {
                aR0[c][0] = *(const v8us*)(ga0 + kn + c * 32);
                aR0[c][1] = *(const v8us*)(ga1 + kn + c * 32);
                bR0[c]    = *(const v8us*)(gb0 + kn + c * 32);
            }
        }
        #pragma unroll
        for (int c = 0; c < 2; ++c) {
            v8bf af[4], bfr[2];
            #pragma unroll
            for (int mt = 0; mt < 4; ++mt)
                af[mt] = *(const v8bf*)&sA0[c][(wm * 64 + mt * 16 + l16) * 32 + quad * 8];
            #pragma unroll
            for (int nt = 0; nt < 2; ++nt)
                bfr[nt] = *(const v8bf*)&sB0[c][(wn * 32 + nt * 16 + l16) * 32 + quad * 8];
            #pragma unroll
            for (int mt = 0; mt < 4; ++mt)
                #pragma unroll
                for (int nt = 0; nt < 2; ++nt)
                    acc[mt][nt] = __builtin_amdgcn_mfma_f32_16x16x32_bf16(
                        af[mt], bfr[nt], acc[mt][nt], 0, 0, 0);
        }

        // ---- half 1 ----
        #pragma unroll
        for (int c = 0; c < 2; ++c) {
            *(v8us*)&sA1[c][oa0] = aR1[c][0];
            *(v8us*)&sA1[c][oa1] = aR1[c][1];
            *(v8us*)&sB1[c][ob]  = bR1[c];
        }
        __syncthreads();
        if (kt + 192 < K) {
            const int kn = kt + 192;
            #pragma unroll
            for (int c = 0; c < 2; ++c) {
                aR1[c][0] = *(const v8us*)(ga0 + kn + c * 32);
                aR1[c][1] = *(const v8us*)(ga1 + kn + c * 32);
                bR1[c]    = *(const v8us*)(gb0 + kn + c * 32);
            }
        }
        #pragma unroll
        for (int c = 0; c < 2; ++c) {
            v8bf af[4], bfr[2];
            #pragma unroll
            for (int mt = 0; mt < 4; ++mt)
                af[mt] = *(const v8bf*)&sA1[c][(wm * 64 + mt * 16 + l16) * 32 + quad * 8];
            #pragma unroll
            for (int nt = 0; nt < 2; ++nt)
                bfr[nt] = *(const v8bf*)&sB1[c][(wn * 32 + nt * 16 + l16) * 32 + quad * 8];
            #pragma unroll
            for (int mt = 0; mt < 4; ++mt)
                #pragma unroll
                for (int nt = 0; nt < 2; ++nt)
                    acc[mt][nt] = __builtin_amdgcn_mfma_f32_16x16x32_bf16(
                        af[mt], bfr[nt], acc[mt][nt], 0, 0, 0);
        }
    }

    #pragma unroll
    for (int mt = 0; mt < 4; ++mt) {
        #pragma unroll
        for (int nt = 0; nt < 2; ++nt) {
            int col = bn * 64 + wn * 32 + nt * 16 + l16;
            float bv = bias ? bias[col] : 0.f;
            #pragma unroll
            for (int r = 0; r < 4; ++r) {
                int row = bm * 128 + wm * 64 + mt * 16 + quad * 4 + r;
                float v = acc[mt][nt][r] + bv;
                if (relu) v = fmaxf(v, 0.f);
                C[(size_t)row * N + col] = f2b(v);
            }
        }
    }
}

// ---------------------------------------------------------------------------
// gemm256 (r21 structure), r25: templated on NF = N-fragments per wave.
// Tile = 256 x (NF*64). NF=4 -> 256x256 (FFN1). NF=3 -> 256x192 (QKV, full
// CU coverage; verified r25, -6.3us). LDS: A 64KB + B NF*16KB.
// 2-phase global_load_lds + st_16x32 swizzle; 8 waves (2M x 4N).
// ---------------------------------------------------------------------------
template<int SPLIT_V, int NF>
__global__ __launch_bounds__(512) void gemm256(
    const unsigned short* __restrict__ A, const unsigned short* __restrict__ BT,
    const float* __restrict__ bias, unsigned short* __restrict__ C,
    unsigned short* __restrict__ VT, int M, int N, int K, int relu)
{
    constexpr int BN = NF * 64;              // 256 or 192
    constexpr int BROWS = BN / 8;            // B rows staged per wave
    __shared__ __align__(16) unsigned short sA[2][256 * 64];
    __shared__ __align__(16) unsigned short sB[2][BN * 64];
    const int tid  = threadIdx.x;
    const int wave = tid >> 6, lane = tid & 63;
    const int wm = wave >> 2, wn = wave & 3;     // 2M x 4N wave grid
    const int quad = lane >> 4, l16 = lane & 15;
    int bm, bn;
    xcd_swizzle(bm, bn);

    const int srow = lane >> 3;
    const int scol = ((lane & 7) * 8) ^ ((lane & 32) ? 16 : 0);
    size_t aoff[4], boff[NF];
    #pragma unroll
    for (int j = 0; j < 4; ++j) {
        int r = wave * 32 + j * 8 + srow;
        aoff[j] = (size_t)(bm * 256 + r) * K + scol;
    }
    #pragma unroll
    for (int j = 0; j < NF; ++j) {
        int r = wave * BROWS + j * 8 + srow;
        boff[j] = (size_t)(bn * BN + r) * K + scol;
    }
    const int lds0A = wave * 32 * 64;        // shorts; +j*512 per issue
    const int lds0B = wave * BROWS * 64;

    // ds_read swizzle: logical k-col quad*8 -> phys ^16 iff row&4 (= l16&4)
    const int ksw = (quad * 8) ^ ((l16 & 4) ? 16 : 0);

    v4f acc[8][NF];
    #pragma unroll
    for (int i = 0; i < 8; ++i)
        #pragma unroll
        for (int j = 0; j < NF; ++j)
            acc[i][j] = (v4f){0.f, 0.f, 0.f, 0.f};

    const int NT = K >> 6;
    #pragma unroll
    for (int j = 0; j < 4; ++j)
        gload16(A  + aoff[j], &sA[0][lds0A + j * 512]);
    #pragma unroll
    for (int j = 0; j < NF; ++j)
        gload16(BT + boff[j], &sB[0][lds0B + j * 512]);
    __syncthreads();

    for (int t = 0; t < NT; ++t) {
        const int buf = t & 1;
        if (t + 1 < NT) {
            const int ktn = (t + 1) << 6;
            #pragma unroll
            for (int j = 0; j < 4; ++j)
                gload16(A  + aoff[j] + ktn, &sA[buf ^ 1][lds0A + j * 512]);
            #pragma unroll
            for (int j = 0; j < NF; ++j)
                gload16(BT + boff[j] + ktn, &sB[buf ^ 1][lds0B + j * 512]);
        }

        v8bf bfr[NF][2];
        #pragma unroll
        for (int nt2 = 0; nt2 < NF; ++nt2)
            #pragma unroll
            for (int kc = 0; kc < 2; ++kc)
                bfr[nt2][kc] = *(const v8bf*)&sB[buf][
                    (wn * (NF * 16) + nt2 * 16 + l16) * 64 + kc * 32 + ksw];
        #pragma unroll
        for (int mq = 0; mq < 2; ++mq) {
            v8bf af[4][2];
            #pragma unroll
            for (int mt2 = 0; mt2 < 4; ++mt2)
                #pragma unroll
                for (int kc = 0; kc < 2; ++kc)
                    af[mt2][kc] = *(const v8bf*)&sA[buf][
                        (wm * 128 + mq * 64 + mt2 * 16 + l16) * 64 + kc * 32 + ksw];
            #pragma unroll
            for (int mt2 = 0; mt2 < 4; ++mt2)
                #pragma unroll
                for (int nt2 = 0; nt2 < NF; ++nt2)
                    #pragma unroll
                    for (int kc = 0; kc < 2; ++kc)
                        acc[mq * 4 + mt2][nt2] =
                            __builtin_amdgcn_mfma_f32_16x16x32_bf16(
                                af[mt2][kc], bfr[nt2][kc],
                                acc[mq * 4 + mt2][nt2], 0, 0, 0);
        }
        __syncthreads();   // drains vmcnt (tile t+1 landed) + lgkm (reads done)
    }

    #pragma unroll
    for (int mt = 0; mt < 8; ++mt) {
        int row = bm * 256 + wm * 128 + mt * 16 + quad * 4;
        #pragma unroll
        for (int nt = 0; nt < NF; ++nt) {
            int c0 = bn * BN + wn * (NF * 16) + nt * 16;
            int col = c0 + l16;
            float bv = bias ? bias[col] : 0.f;
            if (SPLIT_V && (c0 % 192) >= 128) {
                int hh = c0 / 192;
                int d  = (c0 % 192) - 128 + l16;
                int bb = row >> 11;
                int s  = row & 2047;
                v4us st;
                #pragma unroll
                for (int r = 0; r < 4; ++r)
                    st[r] = f2b(acc[mt][nt][r] + bv);
                *(v4us*)&VT[((size_t)(bb * 16 + hh) * 64 + d) * 2048 + s] = st;
            } else {
                float qs = (SPLIT_V && (c0 % 192) < 64) ? 0.18033688f : 1.0f;
                #pragma unroll
                for (int r = 0; r < 4; ++r) {
                    float v = (acc[mt][nt][r] + bv) * qs;
                    if (relu) v = fmaxf(v, 0.f);
                    C[(size_t)(row + r) * N + col] = f2b(v);
                }
            }
        }
    }
}

// ---------------------------------------------------------------------------
// MFMA flash attention v12 (r26, verified): 256 q-rows/block (32 q/wave x
// 8 waves), grid 256. Single-barrier double-buffered K/V LDS. LDS 73728 B.
// ---------------------------------------------------------------------------
__global__ __launch_bounds__(512) void attn_mfma(
    const unsigned short* __restrict__ qkv, const unsigned short* __restrict__ VT,
    unsigned short* __restrict__ av)
{
    __shared__ __align__(16) unsigned short sK[2][64 * 72];
    __shared__ __align__(16) unsigned short sVT[2][64 * 72];
    __shared__ __align__(16) unsigned short sP[8][32 * 72];
    const int tid  = threadIdx.x;
    const int wave = tid >> 6, lane = tid & 63;
    const int quad = lane >> 4, l16 = lane & 15;
    const int blk = blockIdx.x;
    const int xcd = blk & 7, local = blk >> 3;   // 256 blocks: local in [0,32)
    const int bh = xcd * 4 + (local & 3);        // all q-blocks of a bh on one XCD
    const int qb = local >> 2;                   // [0,8): 256-row q-block
    const int h = bh & 15, b = bh >> 4;
    const int row0 = b * 2048;
    const int qbase = row0 + qb * 256 + wave * 32;
    const size_t qoff = (size_t)h * 192;
    const size_t koff = qoff + 64;

    v8bf qf[2][2];
    #pragma unroll
    for (int qt = 0; qt < 2; ++qt)
        #pragma unroll
        for (int kc = 0; kc < 2; ++kc)
            qf[qt][kc] = *(const v8bf*)&qkv[(size_t)(qbase + qt * 16 + l16) * 3072
                                            + qoff + kc * 32 + quad * 8];

    v4f o[4][2];
    #pragma unroll
    for (int dt = 0; dt < 4; ++dt)
        #pragma unroll
        for (int qt = 0; qt < 2; ++qt)
            o[dt][qt] = (v4f){0.f, 0.f, 0.f, 0.f};
    float ll[2] = {0.f, 0.f};

    // staging: 512 threads cover 64x64 K tile and 64x64 V tile, 1 v8us each
    const int k_key = tid >> 3, k_oct = (tid & 7) * 8;
    const unsigned short* gK = qkv + (size_t)(row0 + k_key) * 3072 + koff + k_oct;
    const unsigned short* gV = VT + ((size_t)bh * 64 + k_key) * 2048 + k_oct;
    const size_t stepK = (size_t)64 * 3072;
    const size_t stepV = 64;

    v8us kreg = *(const v8us*)gK;
    v8us vreg = *(const v8us*)gV;
    gK += stepK; gV += stepV;

    for (int kt = 0; kt < 32; ++kt) {
        const int cur = kt & 1;
        *(v8us*)&sK[cur][k_key * 72 + k_oct]  = kreg;
        *(v8us*)&sVT[cur][k_key * 72 + k_oct] = vreg;
        __syncthreads();
        if (kt < 31) {
            kreg = *(const v8us*)gK;
            vreg = *(const v8us*)gV;
            gK += stepK; gV += stepV;
        }

        v4f sc[4][2];
        #pragma unroll
        for (int kk = 0; kk < 4; ++kk) {
            #pragma unroll
            for (int qt = 0; qt < 2; ++qt)
                sc[kk][qt] = (v4f){0.f, 0.f, 0.f, 0.f};
            #pragma unroll
            for (int kc = 0; kc < 2; ++kc) {
                v8bf ak = *(const v8bf*)&sK[cur][(kk * 16 + l16) * 72 + kc * 32 + quad * 8];
                #pragma unroll
                for (int qt = 0; qt < 2; ++qt)
                    sc[kk][qt] = __builtin_amdgcn_mfma_f32_16x16x32_bf16(
                        ak, qf[qt][kc], sc[kk][qt], 0, 0, 0);
            }
        }

        #pragma unroll
        for (int qt = 0; qt < 2; ++qt) {
            float ps = 0.f;
            #pragma unroll
            for (int kk = 0; kk < 4; ++kk) {
                v4bf pk;
                #pragma unroll
                for (int rr = 0; rr < 4; ++rr) {
                    float p = __builtin_amdgcn_exp2f(sc[kk][qt][rr]);
                    ps += p;
                    pk[rr] = (__bf16)p;
                }
                *(v4bf*)&sP[wave][(qt * 16 + l16) * 72 + kk * 16 + quad * 4] = pk;
            }
            ll[qt] += ps;
        }

        __asm__ volatile("s_waitcnt lgkmcnt(0)" ::: "memory");

        #pragma unroll
        for (int c = 0; c < 2; ++c) {
            v8bf pb[2];
            #pragma unroll
            for (int qt = 0; qt < 2; ++qt) {
                union { v8bf v; v8us u; } u;
                u.u = *(const v8us*)&sP[wave][(qt * 16 + l16) * 72 + c * 32 + quad * 8];
                pb[qt] = u.v;
            }
            #pragma unroll
            for (int dt = 0; dt < 4; ++dt) {
                v8bf va = *(const v8bf*)&sVT[cur][(dt * 16 + l16) * 72 + c * 32 + quad * 8];
                #pragma unroll
                for (int qt = 0; qt < 2; ++qt)
                    o[dt][qt] = __builtin_amdgcn_mfma_f32_16x16x32_bf16(
                        va, pb[qt], o[dt][qt], 0, 0, 0);
            }
        }
    }

    #pragma unroll
    for (int qt = 0; qt < 2; ++qt) {
        float l = ll[qt];
        l += __shfl_xor(l, 16, 64);
        l += __shfl_xor(l, 32, 64);
        float inv = 1.f / l;
        int qrow = qbase + qt * 16 + l16;
        #pragma unroll
        for (int dt = 0; dt < 4; ++dt) {
            v4bf st;
            #pragma unroll
            for (int rr = 0; rr < 4; ++rr)
                st[rr] = (__bf16)(o[dt][qt][rr] * inv);
            *(v4bf*)&av[(size_t)qrow * 1024 + h * 64 + dt * 16 + quad * 4] = st;
        }
    }
}

// ---------------------------------------------------------------------------
// LN1 body (residual f32, out bf16, in-place safe).
// ---------------------------------------------------------------------------
__device__ __forceinline__ void ln_row_f32res(
    const unsigned short* __restrict__ a, const float* __restrict__ resid,
    const float* __restrict__ gamma, const float* __restrict__ beta,
    unsigned short* __restrict__ outp, int row, int tid)
{
    const size_t base = (size_t)row * 1024;
    const int c0 = tid * 4;
    ushort4 avv = *(const ushort4*)&a[base + c0];
    float4 rv = *(const float4*)&resid[base + c0];
    float y[4];
    y[0] = b2f(avv.x) + rv.x;
    y[1] = b2f(avv.y) + rv.y;
    y[2] = b2f(avv.z) + rv.z;
    y[3] = b2f(avv.w) + rv.w;
    float s  = y[0] + y[1] + y[2] + y[3];
    float ss = y[0]*y[0] + y[1]*y[1] + y[2]*y[2] + y[3]*y[3];
    #pragma unroll
    for (int off = 32; off; off >>= 1) {
        s  += __shfl_xor(s, off, 64);
        ss += __shfl_xor(ss, off, 64);
    }
    __shared__ float red[8];
    int wave = tid >> 6, lane = tid & 63;
    if (lane == 0) { red[wave] = s; red[4 + wave] = ss; }
    __syncthreads();
    s  = red[0] + red[1] + red[2] + red[3];
    ss = red[4] + red[5] + red[6] + red[7];
    float mean = s * (1.f / 1024.f);
    float var  = ss * (1.f / 1024.f) - mean * mean;
    float rstd = rsqrtf(var + 1e-5f);
    float4 gv = *(const float4*)&gamma[c0];
    float4 bv = *(const float4*)&beta[c0];
    ushort4 ov;
    ov.x = f2b(gv.x * (y[0] - mean) * rstd + bv.x);
    ov.y = f2b(gv.y * (y[1] - mean) * rstd + bv.y);
    ov.z = f2b(gv.z * (y[2] - mean) * rstd + bv.z);
    ov.w = f2b(gv.w * (y[3] - mean) * rstd + bv.w);
    *(ushort4*)&outp[base + c0] = ov;
}

// ---------------------------------------------------------------------------
// r23: LN1 (4096 rows) + W2T transpose (1024 tiles) fused into one launch.
// ---------------------------------------------------------------------------
__global__ __launch_bounds__(256) void ln1_w2t_fused(
    const unsigned short* __restrict__ a, const float* __restrict__ x,
    const float* __restrict__ gamma, const float* __restrict__ beta,
    unsigned short* __restrict__ h_out,
    const float* __restrict__ W2, unsigned short* __restrict__ W2T)
{
    const int b = blockIdx.x, tid = threadIdx.x;
    if (b < 4096) {
        ln_row_f32res(a, x, gamma, beta, h_out, b, tid);
    } else {
        int lb = b - 4096;                       // W2: [4096][1024] -> 64x16 tiles
        transpose_tile(W2, W2T, 4096, 1024, (lb / 16) * 64, (lb % 16) * 64, tid);
    }
}

// ---------------------------------------------------------------------------
// Fused residual-add + LayerNorm (standalone, used for LN2).
// ---------------------------------------------------------------------------
template<int RES_F32, int OUT_F32>
__global__ __launch_bounds__(256) void ln_fused(
    const unsigned short* __restrict__ a, const void* __restrict__ residv,
    const float* __restrict__ gamma, const float* __restrict__ beta,
    void* __restrict__ outv)
{
    const int row = blockIdx.x, tid = threadIdx.x;
    const size_t base = (size_t)row * 1024;
    const int c0 = tid * 4;
    ushort4 avv = *(const ushort4*)&a[base + c0];
    float y[4];
    if (RES_F32) {
        float4 rv = *(const float4*)((const float*)residv + base + c0);
        y[0] = b2f(avv.x) + rv.x;
        y[1] = b2f(avv.y) + rv.y;
        y[2] = b2f(avv.z) + rv.z;
        y[3] = b2f(avv.w) + rv.w;
    } else {
        ushort4 rv = *(const ushort4*)((const unsigned short*)residv + base + c0);
        y[0] = b2f(avv.x) + b2f(rv.x);
        y[1] = b2f(avv.y) + b2f(rv.y);
        y[2] = b2f(avv.z) + b2f(rv.z);
        y[3] = b2f(avv.w) + b2f(rv.w);
    }
    float s  = y[0] + y[1] + y[2] + y[3];
    float ss = y[0]*y[0] + y[1]*y[1] + y[2]*y[2] + y[3]*y[3];
    #pragma unroll
    for (int off = 32; off; off >>= 1) {
        s  += __shfl_xor(s, off, 64);
        ss += __shfl_xor(ss, off, 64);
    }
    __shared__ float red[8];
    int wave = tid >> 6, lane = tid & 63;
    if (lane == 0) { red[wave] = s; red[4 + wave] = ss; }
    __syncthreads();
    s  = red[0] + red[1] + red[2] + red[3];
    ss = red[4] + red[5] + red[6] + red[7];
    float mean = s * (1.f / 1024.f);
    float var  = ss * (1.f / 1024.f) - mean * mean;
    float rstd = rsqrtf(var + 1e-5f);
    float4 gv = *(const float4*)&gamma[c0];
    float4 bv = *(const float4*)&beta[c0];
    float r0 = gv.x * (y[0] - mean) * rstd + bv.x;
    float r1 = gv.y * (y[1] - mean) * rstd + bv.y;
    float r2 = gv.z * (y[2] - mean) * rstd + bv.z;
    float r3 = gv.w * (y[3] - mean) * rstd + bv.w;
    if (OUT_F32) {
        float4 ov = {r0, r1, r2, r3};
        *(float4*)((float*)outv + base + c0) = ov;
    } else {
        ushort4 ov;
        ov.x = f2b(r0); ov.y = f2b(r1); ov.z = f2b(r2); ov.w = f2b(r3);
        *(ushort4*)((unsigned short*)outv + base + c0) = ov;
    }
}

// ---------------------------------------------------------------------------
// Final pipeline (r26 verified best, 325.6us; 8 launches), ws map:
//  R0[0..12M): qkv Q/K -> ffn1(16M)
//  R0[12M..15M): WqkvT   R0[15M..16M): WoT
//  R1: VT -> attn_out -> h (LN1 in-place) -> residual for LN2
//  R2: xb -> av -> W2T
//  R3: W1T -> ffn2
// ---------------------------------------------------------------------------
extern "C" void kernel_launch(void* const* d_in, const int* in_sizes, int n_in,
                              void* d_out, int out_size, void* d_ws, size_t ws_size,
                              hipStream_t stream)
{
    (void)in_sizes; (void)n_in; (void)out_size; (void)ws_size;
    const float* x    = (const float*)d_in[0];
    const float* Wqkv = (const float*)d_in[1];
    const float* bqkv = (const float*)d_in[2];
    const float* Wo   = (const float*)d_in[3];
    const float* bo   = (const float*)d_in[4];
    const float* g1   = (const float*)d_in[5];
    const float* be1  = (const float*)d_in[6];
    const float* W1   = (const float*)d_in[7];
    const float* b1   = (const float*)d_in[8];
    const float* W2   = (const float*)d_in[9];
    const float* b2   = (const float*)d_in[10];
    const float* g2   = (const float*)d_in[11];
    const float* be2  = (const float*)d_in[12];
    float* out = (float*)d_out;

    unsigned short* R0 = (unsigned short*)d_ws;
    unsigned short* R1 = R0 + (size_t)16 * 1024 * 1024;
    unsigned short* R2 = R1 + (size_t)4 * 1024 * 1024;
    unsigned short* R3 = R2 + (size_t)4 * 1024 * 1024;
    unsigned short* WqkvT = R0 + (size_t)12 * 1024 * 1024;
    unsigned short* WoT   = R0 + (size_t)15 * 1024 * 1024;

    const int M = 4096;
    dim3 blk(256);

    // 1. prep: xb (R2), WqkvT, W1T (R3), WoT — one launch
    prep_fused<<<dim3(4096 + 768 + 1024 + 256), blk, 0, stream>>>(
        x, R2, Wqkv, WqkvT, W1, R3, Wo, WoT);
    // 2. qkv: Q(pre-scaled)/K -> R0, V transposed -> VT (R1); 256x192 tile
    gemm256<1, 3><<<dim3(16, 16), dim3(512), 0, stream>>>(R2, WqkvT, bqkv, R0, R1, M, 3072, 1024, 0);
    // 3. attention -> av (R2; xb dead): 256 q-rows/block, grid 256
    attn_mfma<<<dim3(256), dim3(512), 0, stream>>>(R0, R1, R2);
    // 4. attn_out = av @ Wo + bo -> R1 (VT dead)
    gemm_bt_n64<<<dim3(16, 32), blk, 0, stream>>>(R2, WoT, bo, R1, M, 1024, 1024, 0);
    // 5. h = LN1(attn_out + x) -> R1 in-place  +  W2T -> R2 (av dead) — fused
    ln1_w2t_fused<<<dim3(4096 + 1024), blk, 0, stream>>>(R1, x, g1, be1, R1, W2, R2);
    // 6. ffn1 = relu(h @ W1 + b1) -> R0 (qkv/WqkvT/WoT dead)
    gemm256<0, 4><<<dim3(16, 16), dim3(512), 0, stream>>>(R1, R3, b1, R0, nullptr, M, 4096, 1024, 1);
    // 7. ffn2 = ffn1 @ W2 + b2 -> R3 (W1T dead)
    gemm_bt_n64<<<dim3(16, 32), blk, 0, stream>>>(R0, R2, b2, R3, M, 1024, 4096, 0);
    // 8. out = LN2(ffn2 + h)
    ln_fused<0, 1><<<dim3(4096), blk, 0, stream>>>(R3, R1, g2, be2, out);
}